// Round 4
// baseline (676.245 us; speedup 1.0000x reference)
//
#include <hip/hip_runtime.h>

#define T_TOK  2048
#define DIMD   1024
#define INTERI 512
#define NEXP   16
#define NSEG   17   // 16 routed + 1 shared (index 16)

typedef __bf16 bf16x8 __attribute__((ext_vector_type(8)));
typedef float  f32x4  __attribute__((ext_vector_type(4)));

// ---------- helpers ----------
__device__ __forceinline__ unsigned short f2b(float f) {
    union { float f; unsigned int u; } c; c.f = f;
    unsigned int u = c.u;
    unsigned int r = (u + 0x7FFFu + ((u >> 16) & 1u)) >> 16;  // RNE
    return (unsigned short)r;
}

// ---------- fp32 -> bf16 conversion, all 7 tensors in one launch ----------
__global__ __launch_bounds__(256) void cvt_all_kernel(
    const float* __restrict__ x,  const float* __restrict__ w1,
    const float* __restrict__ w3, const float* __restrict__ w2,
    const float* __restrict__ ws1, const float* __restrict__ ws3,
    const float* __restrict__ ws2,
    unsigned short* __restrict__ xb,  unsigned short* __restrict__ w1b,
    unsigned short* __restrict__ w3b, unsigned short* __restrict__ w2b,
    unsigned short* __restrict__ ws1b, unsigned short* __restrict__ ws3b,
    unsigned short* __restrict__ ws2b)
{
    int g = blockIdx.x * 256 + threadIdx.x;
    const float* s; unsigned short* d; int i;
    if      (g < 524288)  { s = x;   d = xb;   i = g; }
    else if (g < 2621440) { s = w1;  d = w1b;  i = g - 524288; }
    else if (g < 4718592) { s = w3;  d = w3b;  i = g - 2621440; }
    else if (g < 6815744) { s = w2;  d = w2b;  i = g - 4718592; }
    else if (g < 6946816) { s = ws1; d = ws1b; i = g - 6815744; }
    else if (g < 7077888) { s = ws3; d = ws3b; i = g - 6946816; }
    else                  { s = ws2; d = ws2b; i = g - 7077888; }
    float4 v = ((const float4*)s)[i];
    ushort4 o;
    o.x = f2b(v.x); o.y = f2b(v.y); o.z = f2b(v.z); o.w = f2b(v.w);
    ((ushort4*)d)[i] = o;
}

// ---------- gate ----------
__global__ __launch_bounds__(256) void gate_kernel(
    const float* __restrict__ x, const float* __restrict__ gw,
    const float* __restrict__ gb,
    int* __restrict__ counts, int* __restrict__ lst, float* __restrict__ lstw)
{
    int tok  = blockIdx.x * 4 + (threadIdx.x >> 6);   // one wave per token
    int lane = threadIdx.x & 63;
    const float* xp = x + (size_t)tok * DIMD;
    float xv[16];
#pragma unroll
    for (int j = 0; j < 16; ++j) xv[j] = xp[j * 64 + lane];

    float sc[16];
#pragma unroll
    for (int e = 0; e < 16; ++e) {
        const float* gwe = gw + e * DIMD;
        float p = 0.f;
#pragma unroll
        for (int j = 0; j < 16; ++j) p += xv[j] * gwe[j * 64 + lane];
#pragma unroll
        for (int o = 32; o; o >>= 1) p += __shfl_xor(p, o, 64);
        sc[e] = p;
    }
    if (lane != 0) return;

    float orig[16], s[16];
#pragma unroll
    for (int e = 0; e < 16; ++e) {
        orig[e] = 1.f / (1.f + expf(-sc[e]));
        s[e] = orig[e] + gb[e];
    }
    float gmax[4];
#pragma unroll
    for (int g = 0; g < 4; ++g) {
        float m = s[4 * g];
        for (int j = 1; j < 4; ++j) m = fmaxf(m, s[4 * g + j]);
        gmax[g] = m;
    }
    int g0 = 0;
    for (int g = 1; g < 4; ++g) if (gmax[g] > gmax[g0]) g0 = g;
    int g1 = -1;
    for (int g = 0; g < 4; ++g) { if (g == g0) continue; if (g1 < 0 || gmax[g] > gmax[g1]) g1 = g; }
    unsigned keep = (0xFu << (4 * g0)) | (0xFu << (4 * g1));
    unsigned used = 0;
    for (int j = 0; j < 4; ++j) {
        int best = -1;
        for (int e = 0; e < 16; ++e) {
            if (!((keep >> e) & 1u) || ((used >> e) & 1u)) continue;
            if (best < 0 || s[e] > s[best]) best = e;
        }
        used |= 1u << best;
        float w = orig[best];
        int pos = atomicAdd(&counts[best], 1);
        lst [best * T_TOK + pos] = tok;
        lstw[best * T_TOK + pos] = w;
    }
}

// ---------- GEMM1: register-only, no LDS, no barriers ----------
// Wave tile: 64m x 32n, dual output (h1,h3). Block = 4 waves spanning 128 n-cols.
// grid (32, 4, 17). Fragments loaded straight from global (L2/L3-resident).
__global__ __launch_bounds__(256) void gemm1_kernel(
    const unsigned short* __restrict__ xb,
    const unsigned short* __restrict__ w1b,
    const unsigned short* __restrict__ w3b,
    const unsigned short* __restrict__ ws1b,
    const unsigned short* __restrict__ ws3b,
    const int* __restrict__ counts,
    const int* __restrict__ lst,
    unsigned short* __restrict__ H)
{
    const int e   = blockIdx.z;
    const int n_e = (e == NEXP) ? T_TOK : counts[e];
    const int m0  = blockIdx.x * 64;
    if (m0 >= n_e) return;

    const int tid  = threadIdx.x;
    const int wave = tid >> 6;
    const int lane = tid & 63;
    const int quad = lane >> 4;
    const int lrow = lane & 15;
    const int n0   = blockIdx.y * 128 + wave * 32;

    const unsigned short* w1p = (e == NEXP) ? ws1b : w1b + (size_t)e * INTERI * DIMD;
    const unsigned short* w3p = (e == NEXP) ? ws3b : w3b + (size_t)e * INTERI * DIMD;
    const int* lste = lst + e * T_TOK;

    // fragment base pointers: A rows gathered by token; k-offset = quad*8
    const unsigned short* pA[4];
#pragma unroll
    for (int t = 0; t < 4; ++t) {
        int r = m0 + t * 16 + lrow;
        int rr = (r < n_e) ? r : (n_e - 1);
        int tok = (e == NEXP) ? rr : lste[rr];
        pA[t] = xb + (size_t)tok * DIMD + quad * 8;
    }
    const unsigned short* pB1[2];
    const unsigned short* pB3[2];
#pragma unroll
    for (int t = 0; t < 2; ++t) {
        pB1[t] = w1p + (size_t)(n0 + t * 16 + lrow) * DIMD + quad * 8;
        pB3[t] = w3p + (size_t)(n0 + t * 16 + lrow) * DIMD + quad * 8;
    }

    f32x4 acc1[4][2], acc3[4][2];
    const f32x4 zero = {0.f, 0.f, 0.f, 0.f};
#pragma unroll
    for (int i = 0; i < 4; ++i)
#pragma unroll
        for (int j = 0; j < 2; ++j) { acc1[i][j] = zero; acc3[i][j] = zero; }

    bf16x8 a[2][4], b1[2][2], b3[2][2];

#define LD1(buf, kk) do { \
    _Pragma("unroll") for (int t = 0; t < 4; ++t) a[buf][t]  = *(const bf16x8*)(pA[t]  + (kk)); \
    _Pragma("unroll") for (int t = 0; t < 2; ++t) b1[buf][t] = *(const bf16x8*)(pB1[t] + (kk)); \
    _Pragma("unroll") for (int t = 0; t < 2; ++t) b3[buf][t] = *(const bf16x8*)(pB3[t] + (kk)); \
} while (0)

#define MM1(buf) do { \
    _Pragma("unroll") for (int i = 0; i < 4; ++i) \
        _Pragma("unroll") for (int j = 0; j < 2; ++j) { \
            acc1[i][j] = __builtin_amdgcn_mfma_f32_16x16x32_bf16(a[buf][i], b1[buf][j], acc1[i][j], 0, 0, 0); \
            acc3[i][j] = __builtin_amdgcn_mfma_f32_16x16x32_bf16(a[buf][i], b3[buf][j], acc3[i][j], 0, 0, 0); \
        } \
} while (0)

    LD1(0, 0);
#pragma unroll
    for (int k = 0; k < DIMD; k += 64) {
        LD1(1, k + 32);
        MM1(0);
        if (k + 64 < DIMD) LD1(0, k + 64);
        MM1(1);
    }
#undef LD1
#undef MM1

    unsigned short* Hseg = H + (size_t)e * T_TOK * INTERI;
#pragma unroll
    for (int i = 0; i < 4; ++i) {
        int rbase = m0 + i * 16 + quad * 4;
#pragma unroll
        for (int r = 0; r < 4; ++r) {
            int row = rbase + r;
            if (row >= n_e) continue;
            unsigned short* hrow = Hseg + (size_t)row * INTERI + n0 + lrow;
#pragma unroll
            for (int j = 0; j < 2; ++j) {
                float v1 = acc1[i][j][r];
                float v3 = acc3[i][j][r];
                float hv = (v1 / (1.f + __expf(-v1))) * v3;   // silu(v1)*v3
                hrow[j * 16] = f2b(hv);
            }
        }
    }
}

// ---------- GEMM2: register-only, no LDS, no barriers ----------
// Wave tile: 64m x 64n. Block = 4 waves spanning 256 n-cols. grid (32, 4, 17).
__global__ __launch_bounds__(256) void gemm2_kernel(
    const unsigned short* __restrict__ H,
    const unsigned short* __restrict__ w2b,
    const unsigned short* __restrict__ ws2b,
    const int* __restrict__ counts,
    const int* __restrict__ lst,
    const float* __restrict__ lstw,
    float* __restrict__ y)
{
    const int e   = blockIdx.z;
    const int n_e = (e == NEXP) ? T_TOK : counts[e];
    const int m0  = blockIdx.x * 64;
    if (m0 >= n_e) return;

    const int tid  = threadIdx.x;
    const int wave = tid >> 6;
    const int lane = tid & 63;
    const int quad = lane >> 4;
    const int lrow = lane & 15;
    const int n0   = blockIdx.y * 256 + wave * 64;

    const unsigned short* w2p  = (e == NEXP) ? ws2b : w2b + (size_t)e * DIMD * INTERI;
    const unsigned short* Hseg = H + (size_t)e * T_TOK * INTERI;

    const unsigned short* pA[4];
#pragma unroll
    for (int t = 0; t < 4; ++t) {
        int r = m0 + t * 16 + lrow;
        int rr = (r < n_e) ? r : (n_e - 1);
        pA[t] = Hseg + (size_t)rr * INTERI + quad * 8;
    }
    const unsigned short* pB[4];
#pragma unroll
    for (int t = 0; t < 4; ++t)
        pB[t] = w2p + (size_t)(n0 + t * 16 + lrow) * INTERI + quad * 8;

    f32x4 acc[4][4];
    const f32x4 zero = {0.f, 0.f, 0.f, 0.f};
#pragma unroll
    for (int i = 0; i < 4; ++i)
#pragma unroll
        for (int j = 0; j < 4; ++j) acc[i][j] = zero;

    bf16x8 a[2][4], b[2][4];

#define LD2(buf, kk) do { \
    _Pragma("unroll") for (int t = 0; t < 4; ++t) a[buf][t] = *(const bf16x8*)(pA[t] + (kk)); \
    _Pragma("unroll") for (int t = 0; t < 4; ++t) b[buf][t] = *(const bf16x8*)(pB[t] + (kk)); \
} while (0)

#define MM2(buf) do { \
    _Pragma("unroll") for (int i = 0; i < 4; ++i) \
        _Pragma("unroll") for (int j = 0; j < 4; ++j) \
            acc[i][j] = __builtin_amdgcn_mfma_f32_16x16x32_bf16(a[buf][i], b[buf][j], acc[i][j], 0, 0, 0); \
} while (0)

    LD2(0, 0);
#pragma unroll
    for (int k = 0; k < INTERI; k += 64) {
        LD2(1, k + 32);
        MM2(0);
        if (k + 64 < INTERI) LD2(0, k + 64);
        MM2(1);
    }
#undef LD2
#undef MM2

#pragma unroll
    for (int i = 0; i < 4; ++i) {
        int rbase = m0 + i * 16 + quad * 4;
#pragma unroll
        for (int r = 0; r < 4; ++r) {
            int row = rbase + r;
            if (row >= n_e) continue;
            int tok; float wt;
            if (e == NEXP) { tok = row; wt = 1.f; }
            else { tok = lst[e * T_TOK + row]; wt = lstw[e * T_TOK + row]; }
            float* yrow = y + (size_t)tok * DIMD + n0 + lrow;
#pragma unroll
            for (int j = 0; j < 4; ++j)
                atomicAdd(&yrow[j * 16], wt * acc[i][j][r]);
        }
    }
}

// ---------- launcher ----------
extern "C" void kernel_launch(void* const* d_in, const int* in_sizes, int n_in,
                              void* d_out, int out_size, void* d_ws, size_t ws_size,
                              hipStream_t stream)
{
    const float* x   = (const float*)d_in[0];
    const float* gw  = (const float*)d_in[1];
    const float* gb  = (const float*)d_in[2];
    const float* w1  = (const float*)d_in[3];
    const float* w2  = (const float*)d_in[4];
    const float* w3  = (const float*)d_in[5];
    const float* ws1 = (const float*)d_in[6];
    const float* ws2 = (const float*)d_in[7];
    const float* ws3 = (const float*)d_in[8];

    char* base = (char*)d_ws;
    size_t off = 0;
    auto alloc = [&](size_t bytes) {
        char* q = base + off; off += (bytes + 255) & ~(size_t)255; return q;
    };
    unsigned short* xb   = (unsigned short*)alloc((size_t)T_TOK * DIMD * 2);
    unsigned short* w1b  = (unsigned short*)alloc((size_t)NEXP * INTERI * DIMD * 2);
    unsigned short* w3b  = (unsigned short*)alloc((size_t)NEXP * INTERI * DIMD * 2);
    unsigned short* w2b  = (unsigned short*)alloc((size_t)NEXP * DIMD * INTERI * 2);
    unsigned short* ws1b = (unsigned short*)alloc((size_t)INTERI * DIMD * 2);
    unsigned short* ws3b = (unsigned short*)alloc((size_t)INTERI * DIMD * 2);
    unsigned short* ws2b = (unsigned short*)alloc((size_t)DIMD * INTERI * 2);
    unsigned short* Hb   = (unsigned short*)alloc((size_t)NSEG * T_TOK * INTERI * 2);
    int*            cnts = (int*)alloc(NEXP * 4);
    int*            lstp = (int*)alloc((size_t)NEXP * T_TOK * 4);
    float*          lstw = (float*)alloc((size_t)NEXP * T_TOK * 4);

    hipMemsetAsync(cnts, 0, NEXP * 4, stream);
    hipMemsetAsync(d_out, 0, (size_t)T_TOK * DIMD * 4, stream);

    cvt_all_kernel<<<28160, 256, 0, stream>>>(x, w1, w3, w2, ws1, ws3, ws2,
                                              xb, w1b, w3b, w2b, ws1b, ws3b, ws2b);
    gate_kernel<<<T_TOK / 4, 256, 0, stream>>>(x, gw, gb, cnts, lstp, lstw);
    gemm1_kernel<<<dim3(32, 4, NSEG), 256, 0, stream>>>(xb, w1b, w3b, ws1b, ws3b, cnts, lstp, Hb);
    gemm2_kernel<<<dim3(32, 4, NSEG), 256, 0, stream>>>(Hb, w2b, ws2b, cnts, lstp, lstw, (float*)d_out);
}

// Round 5
// 350.875 us; speedup vs baseline: 1.9273x; 1.9273x over previous
//
#include <hip/hip_runtime.h>

#define T_TOK  2048
#define DIMD   1024
#define INTERI 512
#define NEXP   16
#define NSEG   17   // 16 routed + 1 shared (index 16)

typedef __bf16 bf16x8 __attribute__((ext_vector_type(8)));
typedef float  f32x4  __attribute__((ext_vector_type(4)));

// ---------- helpers ----------
__device__ __forceinline__ unsigned short f2b(float f) {
    union { float f; unsigned int u; } c; c.f = f;
    unsigned int u = c.u;
    unsigned int r = (u + 0x7FFFu + ((u >> 16) & 1u)) >> 16;  // RNE
    return (unsigned short)r;
}

__device__ __forceinline__ void cp16(const unsigned short* g, unsigned short* l) {
    // direct global->LDS, 16B per lane; LDS dest = wave-uniform base + lane*16
    __builtin_amdgcn_global_load_lds(
        (const __attribute__((address_space(1))) unsigned int*)g,
        (__attribute__((address_space(3))) unsigned int*)l,
        16, 0, 0);
}

// ---------- fp32 -> bf16 conversion, all 7 tensors in one launch ----------
__global__ __launch_bounds__(256) void cvt_all_kernel(
    const float* __restrict__ x,  const float* __restrict__ w1,
    const float* __restrict__ w3, const float* __restrict__ w2,
    const float* __restrict__ ws1, const float* __restrict__ ws3,
    const float* __restrict__ ws2,
    unsigned short* __restrict__ xb,  unsigned short* __restrict__ w1b,
    unsigned short* __restrict__ w3b, unsigned short* __restrict__ w2b,
    unsigned short* __restrict__ ws1b, unsigned short* __restrict__ ws3b,
    unsigned short* __restrict__ ws2b)
{
    int g = blockIdx.x * 256 + threadIdx.x;
    const float* s; unsigned short* d; int i;
    if      (g < 524288)  { s = x;   d = xb;   i = g; }
    else if (g < 2621440) { s = w1;  d = w1b;  i = g - 524288; }
    else if (g < 4718592) { s = w3;  d = w3b;  i = g - 2621440; }
    else if (g < 6815744) { s = w2;  d = w2b;  i = g - 4718592; }
    else if (g < 6946816) { s = ws1; d = ws1b; i = g - 6815744; }
    else if (g < 7077888) { s = ws3; d = ws3b; i = g - 6946816; }
    else                  { s = ws2; d = ws2b; i = g - 7077888; }
    float4 v = ((const float4*)s)[i];
    ushort4 o;
    o.x = f2b(v.x); o.y = f2b(v.y); o.z = f2b(v.z); o.w = f2b(v.w);
    ((ushort4*)d)[i] = o;
}

// ---------- gate ----------
__global__ __launch_bounds__(256) void gate_kernel(
    const float* __restrict__ x, const float* __restrict__ gw,
    const float* __restrict__ gb,
    int* __restrict__ counts, int* __restrict__ lst, float* __restrict__ lstw)
{
    int tok  = blockIdx.x * 4 + (threadIdx.x >> 6);   // one wave per token
    int lane = threadIdx.x & 63;
    const float* xp = x + (size_t)tok * DIMD;
    float xv[16];
#pragma unroll
    for (int j = 0; j < 16; ++j) xv[j] = xp[j * 64 + lane];

    float sc[16];
#pragma unroll
    for (int e = 0; e < 16; ++e) {
        const float* gwe = gw + e * DIMD;
        float p = 0.f;
#pragma unroll
        for (int j = 0; j < 16; ++j) p += xv[j] * gwe[j * 64 + lane];
#pragma unroll
        for (int o = 32; o; o >>= 1) p += __shfl_xor(p, o, 64);
        sc[e] = p;
    }
    if (lane != 0) return;

    float orig[16], s[16];
#pragma unroll
    for (int e = 0; e < 16; ++e) {
        orig[e] = 1.f / (1.f + expf(-sc[e]));
        s[e] = orig[e] + gb[e];
    }
    float gmax[4];
#pragma unroll
    for (int g = 0; g < 4; ++g) {
        float m = s[4 * g];
        for (int j = 1; j < 4; ++j) m = fmaxf(m, s[4 * g + j]);
        gmax[g] = m;
    }
    int g0 = 0;
    for (int g = 1; g < 4; ++g) if (gmax[g] > gmax[g0]) g0 = g;
    int g1 = -1;
    for (int g = 0; g < 4; ++g) { if (g == g0) continue; if (g1 < 0 || gmax[g] > gmax[g1]) g1 = g; }
    unsigned keep = (0xFu << (4 * g0)) | (0xFu << (4 * g1));
    unsigned used = 0;
    for (int j = 0; j < 4; ++j) {
        int best = -1;
        for (int e = 0; e < 16; ++e) {
            if (!((keep >> e) & 1u) || ((used >> e) & 1u)) continue;
            if (best < 0 || s[e] > s[best]) best = e;
        }
        used |= 1u << best;
        float w = orig[best];
        int pos = atomicAdd(&counts[best], 1);
        lst [best * T_TOK + pos] = tok;
        lstw[best * T_TOK + pos] = w;
    }
}

// ---------- GEMM1: H = silu(X W1^T) * (X W3^T) ----------
// Tile 64m x 128n, BK=64 (two 32-k panels). XCD-affine flattened grid:
// expert s runs on XCD s%8 so its 2MB of w1+w3 stays hot in that XCD's 4MB L2.
// grid: 2048 routed slots (xcd-major) + 128 shared slots = 2176 blocks.
__global__ __launch_bounds__(256, 4) void gemm1_kernel(
    const unsigned short* __restrict__ xb,
    const unsigned short* __restrict__ w1b,
    const unsigned short* __restrict__ w3b,
    const unsigned short* __restrict__ ws1b,
    const unsigned short* __restrict__ ws3b,
    const int* __restrict__ counts,
    const int* __restrict__ lst,
    unsigned short* __restrict__ H)
{
    int b = blockIdx.x;
    int seg, mt, nt;
    if (b < 2048) {                       // routed: xcd = b&7, seg = xcd + 8*(slot>>7)
        int xcd = b & 7, slot = b >> 3;
        seg = xcd + 8 * (slot >> 7);
        int tile = slot & 127;
        nt = tile & 3; mt = tile >> 2;    // mt 0..31, nt 0..3
    } else {                              // shared expert, spread over all XCDs
        seg = NEXP;
        int tile = b - 2048;
        nt = tile & 3; mt = tile >> 2;
    }
    const int n_e = (seg == NEXP) ? T_TOK : counts[seg];
    const int m0  = mt * 64;
    if (m0 >= n_e) return;
    const int n0  = nt * 128;

    const unsigned short* w1p = (seg == NEXP) ? ws1b : w1b + (size_t)seg * INTERI * DIMD;
    const unsigned short* w3p = (seg == NEXP) ? ws3b : w3b + (size_t)seg * INTERI * DIMD;
    const int* lste = lst + seg * T_TOK;

    __shared__ __align__(16) unsigned short lA [2][64][32];    // 8 KB
    __shared__ __align__(16) unsigned short lB1[2][128][32];   // 16 KB
    __shared__ __align__(16) unsigned short lB3[2][128][32];   // 16 KB

    const int tid  = threadIdx.x;
    const int wave = tid >> 6;
    const int lane = tid & 63;
    const int r4   = tid >> 2;        // 0..63
    const int skg  = (tid & 3) * 8;   // k-elem offset in 32-panel

    // gathered token for this thread's A staging row
    int ra = m0 + r4; if (ra > n_e - 1) ra = n_e - 1;
    int tok = (seg == NEXP) ? ra : lste[ra];
    const unsigned short* gA  = xb  + (size_t)tok * DIMD + skg;
    const unsigned short* gB1a = w1p + (size_t)(n0 + r4) * DIMD + skg;
    const unsigned short* gB1b = w1p + (size_t)(n0 + r4 + 64) * DIMD + skg;
    const unsigned short* gB3a = w3p + (size_t)(n0 + r4) * DIMD + skg;
    const unsigned short* gB3b = w3p + (size_t)(n0 + r4 + 64) * DIMD + skg;

    const int wb = wave * 512;        // wave-uniform LDS elem base (16 rows * 32)

    f32x4 acc1[2][4], acc3[2][4];
    const f32x4 zero = {0.f, 0.f, 0.f, 0.f};
#pragma unroll
    for (int i = 0; i < 2; ++i)
#pragma unroll
        for (int j = 0; j < 4; ++j) { acc1[i][j] = zero; acc3[i][j] = zero; }

    const int wm   = (wave & 1) * 32;   // wave row offset in tile
    const int wn   = (wave >> 1) * 64;  // wave col offset in tile
    const int quad = lane >> 4;
    const int lrow = lane & 15;

    for (int k0 = 0; k0 < DIMD; k0 += 64) {
#pragma unroll
        for (int kk = 0; kk < 2; ++kk) {
            cp16(gA   + k0 + kk * 32, &lA [kk][0][0]  + wb);
            cp16(gB1a + k0 + kk * 32, &lB1[kk][0][0]  + wb);
            cp16(gB1b + k0 + kk * 32, &lB1[kk][64][0] + wb);
            cp16(gB3a + k0 + kk * 32, &lB3[kk][0][0]  + wb);
            cp16(gB3b + k0 + kk * 32, &lB3[kk][64][0] + wb);
        }
        __syncthreads();
#pragma unroll
        for (int kk = 0; kk < 2; ++kk) {
            bf16x8 a[2], b1[4], b3[4];
#pragma unroll
            for (int t = 0; t < 2; ++t)
                a[t] = *(const bf16x8*)&lA[kk][wm + t * 16 + lrow][quad * 8];
#pragma unroll
            for (int t = 0; t < 4; ++t) {
                b1[t] = *(const bf16x8*)&lB1[kk][wn + t * 16 + lrow][quad * 8];
                b3[t] = *(const bf16x8*)&lB3[kk][wn + t * 16 + lrow][quad * 8];
            }
#pragma unroll
            for (int i = 0; i < 2; ++i)
#pragma unroll
                for (int j = 0; j < 4; ++j) {
                    acc1[i][j] = __builtin_amdgcn_mfma_f32_16x16x32_bf16(a[i], b1[j], acc1[i][j], 0, 0, 0);
                    acc3[i][j] = __builtin_amdgcn_mfma_f32_16x16x32_bf16(a[i], b3[j], acc3[i][j], 0, 0, 0);
                }
        }
        __syncthreads();
    }

    unsigned short* Hseg = H + (size_t)seg * T_TOK * INTERI;
#pragma unroll
    for (int i = 0; i < 2; ++i) {
        int rbase = m0 + wm + i * 16 + quad * 4;
#pragma unroll
        for (int r = 0; r < 4; ++r) {
            int row = rbase + r;
            if (row >= n_e) continue;
            unsigned short* hrow = Hseg + (size_t)row * INTERI + n0 + wn + lrow;
#pragma unroll
            for (int j = 0; j < 4; ++j) {
                float v1 = acc1[i][j][r];
                float v3 = acc3[i][j][r];
                float hv = (v1 / (1.f + __expf(-v1))) * v3;   // silu(v1)*v3
                hrow[j * 16] = f2b(hv);
            }
        }
    }
}

// ---------- GEMM2: y += w * (H W2^T), tile 64m x 128n, BK=64, XCD-affine ----------
// grid: 4096 routed slots + 256 shared = 4352 blocks.
__global__ __launch_bounds__(256, 4) void gemm2_kernel(
    const unsigned short* __restrict__ H,
    const unsigned short* __restrict__ w2b,
    const unsigned short* __restrict__ ws2b,
    const int* __restrict__ counts,
    const int* __restrict__ lst,
    const float* __restrict__ lstw,
    float* __restrict__ y)
{
    int b = blockIdx.x;
    int seg, mt, nt;
    if (b < 4096) {
        int xcd = b & 7, slot = b >> 3;
        seg = xcd + 8 * (slot >> 8);
        int tile = slot & 255;
        nt = tile & 7; mt = tile >> 3;    // mt 0..31, nt 0..7
    } else {
        seg = NEXP;
        int tile = b - 4096;
        nt = tile & 7; mt = tile >> 3;
    }
    const int n_e = (seg == NEXP) ? T_TOK : counts[seg];
    const int m0  = mt * 64;
    if (m0 >= n_e) return;
    const int n0  = nt * 128;

    const unsigned short* w2p  = (seg == NEXP) ? ws2b : w2b + (size_t)seg * DIMD * INTERI;
    const unsigned short* Hseg = H + (size_t)seg * T_TOK * INTERI;

    __shared__ __align__(16) unsigned short lA[2][64][32];    // 8 KB
    __shared__ __align__(16) unsigned short lB[2][128][32];   // 16 KB

    const int tid  = threadIdx.x;
    const int wave = tid >> 6;
    const int lane = tid & 63;
    const int r4   = tid >> 2;
    const int skg  = (tid & 3) * 8;

    int ra = m0 + r4; if (ra > n_e - 1) ra = n_e - 1;
    const unsigned short* gA  = Hseg + (size_t)ra * INTERI + skg;
    const unsigned short* gB0 = w2p + (size_t)(n0 + r4) * INTERI + skg;
    const unsigned short* gB1 = w2p + (size_t)(n0 + r4 + 64) * INTERI + skg;

    const int wb = wave * 512;

    f32x4 acc[2][4];
    const f32x4 zero = {0.f, 0.f, 0.f, 0.f};
#pragma unroll
    for (int i = 0; i < 2; ++i)
#pragma unroll
        for (int j = 0; j < 4; ++j) acc[i][j] = zero;

    const int wm   = (wave & 1) * 32;
    const int wn   = (wave >> 1) * 64;
    const int quad = lane >> 4;
    const int lrow = lane & 15;

    for (int k0 = 0; k0 < INTERI; k0 += 64) {
#pragma unroll
        for (int kk = 0; kk < 2; ++kk) {
            cp16(gA  + k0 + kk * 32, &lA[kk][0][0]  + wb);
            cp16(gB0 + k0 + kk * 32, &lB[kk][0][0]  + wb);
            cp16(gB1 + k0 + kk * 32, &lB[kk][64][0] + wb);
        }
        __syncthreads();
#pragma unroll
        for (int kk = 0; kk < 2; ++kk) {
            bf16x8 a[2], bv[4];
#pragma unroll
            for (int t = 0; t < 2; ++t)
                a[t] = *(const bf16x8*)&lA[kk][wm + t * 16 + lrow][quad * 8];
#pragma unroll
            for (int t = 0; t < 4; ++t)
                bv[t] = *(const bf16x8*)&lB[kk][wn + t * 16 + lrow][quad * 8];
#pragma unroll
            for (int i = 0; i < 2; ++i)
#pragma unroll
                for (int j = 0; j < 4; ++j)
                    acc[i][j] = __builtin_amdgcn_mfma_f32_16x16x32_bf16(a[i], bv[j], acc[i][j], 0, 0, 0);
        }
        __syncthreads();
    }

#pragma unroll
    for (int i = 0; i < 2; ++i) {
        int rbase = m0 + wm + i * 16 + quad * 4;
#pragma unroll
        for (int r = 0; r < 4; ++r) {
            int row = rbase + r;
            if (row >= n_e) continue;
            int tok; float wt;
            if (seg == NEXP) { tok = row; wt = 1.f; }
            else { tok = lst[seg * T_TOK + row]; wt = lstw[seg * T_TOK + row]; }
            float* yrow = y + (size_t)tok * DIMD + n0 + wn + lrow;
#pragma unroll
            for (int j = 0; j < 4; ++j)
                atomicAdd(&yrow[j * 16], wt * acc[i][j][r]);
        }
    }
}

// ---------- launcher ----------
extern "C" void kernel_launch(void* const* d_in, const int* in_sizes, int n_in,
                              void* d_out, int out_size, void* d_ws, size_t ws_size,
                              hipStream_t stream)
{
    const float* x   = (const float*)d_in[0];
    const float* gw  = (const float*)d_in[1];
    const float* gb  = (const float*)d_in[2];
    const float* w1  = (const float*)d_in[3];
    const float* w2  = (const float*)d_in[4];
    const float* w3  = (const float*)d_in[5];
    const float* ws1 = (const float*)d_in[6];
    const float* ws2 = (const float*)d_in[7];
    const float* ws3 = (const float*)d_in[8];

    char* base = (char*)d_ws;
    size_t off = 0;
    auto alloc = [&](size_t bytes) {
        char* q = base + off; off += (bytes + 255) & ~(size_t)255; return q;
    };
    unsigned short* xb   = (unsigned short*)alloc((size_t)T_TOK * DIMD * 2);
    unsigned short* w1b  = (unsigned short*)alloc((size_t)NEXP * INTERI * DIMD * 2);
    unsigned short* w3b  = (unsigned short*)alloc((size_t)NEXP * INTERI * DIMD * 2);
    unsigned short* w2b  = (unsigned short*)alloc((size_t)NEXP * DIMD * INTERI * 2);
    unsigned short* ws1b = (unsigned short*)alloc((size_t)INTERI * DIMD * 2);
    unsigned short* ws3b = (unsigned short*)alloc((size_t)INTERI * DIMD * 2);
    unsigned short* ws2b = (unsigned short*)alloc((size_t)DIMD * INTERI * 2);
    unsigned short* Hb   = (unsigned short*)alloc((size_t)NSEG * T_TOK * INTERI * 2);
    int*            cnts = (int*)alloc(NEXP * 4);
    int*            lstp = (int*)alloc((size_t)NEXP * T_TOK * 4);
    float*          lstw = (float*)alloc((size_t)NEXP * T_TOK * 4);

    hipMemsetAsync(cnts, 0, NEXP * 4, stream);
    hipMemsetAsync(d_out, 0, (size_t)T_TOK * DIMD * 4, stream);

    cvt_all_kernel<<<28160, 256, 0, stream>>>(x, w1, w3, w2, ws1, ws3, ws2,
                                              xb, w1b, w3b, w2b, ws1b, ws3b, ws2b);
    gate_kernel<<<T_TOK / 4, 256, 0, stream>>>(x, gw, gb, cnts, lstp, lstw);
    gemm1_kernel<<<2176, 256, 0, stream>>>(xb, w1b, w3b, ws1b, ws3b, cnts, lstp, Hb);
    gemm2_kernel<<<4352, 256, 0, stream>>>(Hb, w2b, ws2b, cnts, lstp, lstw, (float*)d_out);
}

// Round 6
// 272.087 us; speedup vs baseline: 2.4854x; 1.2896x over previous
//
#include <hip/hip_runtime.h>

#define T_TOK  2048
#define DIMD   1024
#define INTERI 512
#define NEXP   16
#define NSEG   17   // 16 routed + 1 shared (index 16)

typedef __bf16 bf16x8 __attribute__((ext_vector_type(8)));
typedef float  f32x4  __attribute__((ext_vector_type(4)));

// ---------- helpers ----------
__device__ __forceinline__ unsigned short f2b(float f) {
    union { float f; unsigned int u; } c; c.f = f;
    unsigned int u = c.u;
    unsigned int r = (u + 0x7FFFu + ((u >> 16) & 1u)) >> 16;  // RNE
    return (unsigned short)r;
}

__device__ __forceinline__ void cp16(const unsigned short* g, unsigned short* l) {
    // direct global->LDS, 16B per lane; LDS dest = wave-uniform base + lane*16
    __builtin_amdgcn_global_load_lds(
        (const __attribute__((address_space(1))) unsigned int*)g,
        (__attribute__((address_space(3))) unsigned int*)l,
        16, 0, 0);
}

// ---------- fp32 -> bf16 conversion, all 7 tensors in one launch ----------
__global__ __launch_bounds__(256) void cvt_all_kernel(
    const float* __restrict__ x,  const float* __restrict__ w1,
    const float* __restrict__ w3, const float* __restrict__ w2,
    const float* __restrict__ ws1, const float* __restrict__ ws3,
    const float* __restrict__ ws2,
    unsigned short* __restrict__ xb,  unsigned short* __restrict__ w1b,
    unsigned short* __restrict__ w3b, unsigned short* __restrict__ w2b,
    unsigned short* __restrict__ ws1b, unsigned short* __restrict__ ws3b,
    unsigned short* __restrict__ ws2b)
{
    int g = blockIdx.x * 256 + threadIdx.x;
    const float* s; unsigned short* d; int i;
    if      (g < 524288)  { s = x;   d = xb;   i = g; }
    else if (g < 2621440) { s = w1;  d = w1b;  i = g - 524288; }
    else if (g < 4718592) { s = w3;  d = w3b;  i = g - 2621440; }
    else if (g < 6815744) { s = w2;  d = w2b;  i = g - 4718592; }
    else if (g < 6946816) { s = ws1; d = ws1b; i = g - 6815744; }
    else if (g < 7077888) { s = ws3; d = ws3b; i = g - 6946816; }
    else                  { s = ws2; d = ws2b; i = g - 7077888; }
    float4 v = ((const float4*)s)[i];
    ushort4 o;
    o.x = f2b(v.x); o.y = f2b(v.y); o.z = f2b(v.z); o.w = f2b(v.w);
    ((ushort4*)d)[i] = o;
}

// ---------- gate phase 1: scores + top-k selection, NO atomics ----------
// sel[t]: packed 4x4-bit expert ids; selw[t]: float4 weights (slot order)
__global__ __launch_bounds__(256) void gate_score_kernel(
    const float* __restrict__ x, const float* __restrict__ gw,
    const float* __restrict__ gb,
    unsigned* __restrict__ sel, float4* __restrict__ selw)
{
    int tok  = blockIdx.x * 4 + (threadIdx.x >> 6);   // one wave per token
    int lane = threadIdx.x & 63;
    const float* xp = x + (size_t)tok * DIMD;
    float xv[16];
#pragma unroll
    for (int j = 0; j < 16; ++j) xv[j] = xp[j * 64 + lane];

    float sc[16];
#pragma unroll
    for (int e = 0; e < 16; ++e) {
        const float* gwe = gw + e * DIMD;
        float p0 = 0.f, p1 = 0.f;
#pragma unroll
        for (int j = 0; j < 16; j += 2) {
            p0 += xv[j]     * gwe[j * 64 + lane];
            p1 += xv[j + 1] * gwe[(j + 1) * 64 + lane];
        }
        float p = p0 + p1;
#pragma unroll
        for (int o = 32; o; o >>= 1) p += __shfl_xor(p, o, 64);
        sc[e] = p;
    }
    if (lane != 0) return;

    float orig[16], s[16];
#pragma unroll
    for (int e = 0; e < 16; ++e) {
        orig[e] = 1.f / (1.f + expf(-sc[e]));
        s[e] = orig[e] + gb[e];
    }
    float gmax[4];
#pragma unroll
    for (int g = 0; g < 4; ++g) {
        float m = s[4 * g];
        for (int j = 1; j < 4; ++j) m = fmaxf(m, s[4 * g + j]);
        gmax[g] = m;
    }
    int g0 = 0;
    for (int g = 1; g < 4; ++g) if (gmax[g] > gmax[g0]) g0 = g;
    int g1 = -1;
    for (int g = 0; g < 4; ++g) { if (g == g0) continue; if (g1 < 0 || gmax[g] > gmax[g1]) g1 = g; }
    unsigned keep = (0xFu << (4 * g0)) | (0xFu << (4 * g1));
    unsigned used = 0;
    unsigned pk = 0;
    float w4[4];
    for (int j = 0; j < 4; ++j) {
        int best = -1;
        for (int e = 0; e < 16; ++e) {
            if (!((keep >> e) & 1u) || ((used >> e) & 1u)) continue;
            if (best < 0 || s[e] > s[best]) best = e;
        }
        used |= 1u << best;
        pk |= ((unsigned)best) << (4 * j);
        w4[j] = orig[best];
    }
    sel[tok] = pk;
    selw[tok] = make_float4(w4[0], w4[1], w4[2], w4[3]);
}

// ---------- gate phase 2: build per-expert token lists, NO atomics ----------
// 16 blocks (one per expert) x 256 threads; ballot + prefix over token chunks.
__global__ __launch_bounds__(256) void build_lists_kernel(
    const unsigned* __restrict__ sel, const float4* __restrict__ selw,
    int* __restrict__ counts, int* __restrict__ lst, float* __restrict__ lstw)
{
    const int e    = blockIdx.x;
    const int tid  = threadIdx.x;
    const int wave = tid >> 6;
    const int lane = tid & 63;

    __shared__ int wsum[4];
    __shared__ int basev;
    if (tid == 0) basev = 0;
    __syncthreads();

    for (int c = 0; c < T_TOK / 256; ++c) {
        int t = c * 256 + tid;
        unsigned s = sel[t];
        int match = -1;
#pragma unroll
        for (int j = 0; j < 4; ++j)
            if (((s >> (4 * j)) & 15u) == (unsigned)e) match = j;
        unsigned long long m = __ballot(match >= 0);
        int wpre = __popcll(m & ((1ull << lane) - 1ull));
        if (lane == 0) wsum[wave] = __popcll(m);
        __syncthreads();
        int pre = basev;
        for (int wv = 0; wv < wave; ++wv) pre += wsum[wv];
        if (match >= 0) {
            int pos = pre + wpre;
            lst [e * T_TOK + pos] = t;
            const float* wp = (const float*)&selw[t];
            lstw[e * T_TOK + pos] = wp[match];
        }
        __syncthreads();
        if (tid == 0) basev += wsum[0] + wsum[1] + wsum[2] + wsum[3];
        __syncthreads();
    }
    if (tid == 0) counts[e] = basev;
}

// ---------- GEMM1: H = silu(X W1^T) * (X W3^T) ----------
// Tile 64m x 128n, BK=64 (two 32-k panels). XCD-affine flattened grid:
// expert s runs on XCD s%8 so its 2MB of w1+w3 stays hot in that XCD's 4MB L2.
__global__ __launch_bounds__(256, 4) void gemm1_kernel(
    const unsigned short* __restrict__ xb,
    const unsigned short* __restrict__ w1b,
    const unsigned short* __restrict__ w3b,
    const unsigned short* __restrict__ ws1b,
    const unsigned short* __restrict__ ws3b,
    const int* __restrict__ counts,
    const int* __restrict__ lst,
    unsigned short* __restrict__ H)
{
    int b = blockIdx.x;
    int seg, mt, nt;
    if (b < 2048) {                       // routed: xcd = b&7, seg = xcd + 8*(slot>>7)
        int xcd = b & 7, slot = b >> 3;
        seg = xcd + 8 * (slot >> 7);
        int tile = slot & 127;
        nt = tile & 3; mt = tile >> 2;    // mt 0..31, nt 0..3
    } else {                              // shared expert, spread over all XCDs
        seg = NEXP;
        int tile = b - 2048;
        nt = tile & 3; mt = tile >> 2;
    }
    const int n_e = (seg == NEXP) ? T_TOK : counts[seg];
    const int m0  = mt * 64;
    if (m0 >= n_e) return;
    const int n0  = nt * 128;

    const unsigned short* w1p = (seg == NEXP) ? ws1b : w1b + (size_t)seg * INTERI * DIMD;
    const unsigned short* w3p = (seg == NEXP) ? ws3b : w3b + (size_t)seg * INTERI * DIMD;
    const int* lste = lst + seg * T_TOK;

    __shared__ __align__(16) unsigned short lA [2][64][32];    // 8 KB
    __shared__ __align__(16) unsigned short lB1[2][128][32];   // 16 KB
    __shared__ __align__(16) unsigned short lB3[2][128][32];   // 16 KB

    const int tid  = threadIdx.x;
    const int wave = tid >> 6;
    const int lane = tid & 63;
    const int r4   = tid >> 2;        // 0..63
    const int skg  = (tid & 3) * 8;   // k-elem offset in 32-panel

    int ra = m0 + r4; if (ra > n_e - 1) ra = n_e - 1;
    int tok = (seg == NEXP) ? ra : lste[ra];
    const unsigned short* gA  = xb  + (size_t)tok * DIMD + skg;
    const unsigned short* gB1a = w1p + (size_t)(n0 + r4) * DIMD + skg;
    const unsigned short* gB1b = w1p + (size_t)(n0 + r4 + 64) * DIMD + skg;
    const unsigned short* gB3a = w3p + (size_t)(n0 + r4) * DIMD + skg;
    const unsigned short* gB3b = w3p + (size_t)(n0 + r4 + 64) * DIMD + skg;

    const int wb = wave * 512;        // wave-uniform LDS elem base (16 rows * 32)

    f32x4 acc1[2][4], acc3[2][4];
    const f32x4 zero = {0.f, 0.f, 0.f, 0.f};
#pragma unroll
    for (int i = 0; i < 2; ++i)
#pragma unroll
        for (int j = 0; j < 4; ++j) { acc1[i][j] = zero; acc3[i][j] = zero; }

    const int wm   = (wave & 1) * 32;   // wave row offset in tile
    const int wn   = (wave >> 1) * 64;  // wave col offset in tile
    const int quad = lane >> 4;
    const int lrow = lane & 15;

    for (int k0 = 0; k0 < DIMD; k0 += 64) {
#pragma unroll
        for (int kk = 0; kk < 2; ++kk) {
            cp16(gA   + k0 + kk * 32, &lA [kk][0][0]  + wb);
            cp16(gB1a + k0 + kk * 32, &lB1[kk][0][0]  + wb);
            cp16(gB1b + k0 + kk * 32, &lB1[kk][64][0] + wb);
            cp16(gB3a + k0 + kk * 32, &lB3[kk][0][0]  + wb);
            cp16(gB3b + k0 + kk * 32, &lB3[kk][64][0] + wb);
        }
        __syncthreads();
#pragma unroll
        for (int kk = 0; kk < 2; ++kk) {
            bf16x8 a[2], b1[4], b3[4];
#pragma unroll
            for (int t = 0; t < 2; ++t)
                a[t] = *(const bf16x8*)&lA[kk][wm + t * 16 + lrow][quad * 8];
#pragma unroll
            for (int t = 0; t < 4; ++t) {
                b1[t] = *(const bf16x8*)&lB1[kk][wn + t * 16 + lrow][quad * 8];
                b3[t] = *(const bf16x8*)&lB3[kk][wn + t * 16 + lrow][quad * 8];
            }
#pragma unroll
            for (int i = 0; i < 2; ++i)
#pragma unroll
                for (int j = 0; j < 4; ++j) {
                    acc1[i][j] = __builtin_amdgcn_mfma_f32_16x16x32_bf16(a[i], b1[j], acc1[i][j], 0, 0, 0);
                    acc3[i][j] = __builtin_amdgcn_mfma_f32_16x16x32_bf16(a[i], b3[j], acc3[i][j], 0, 0, 0);
                }
        }
        __syncthreads();
    }

    unsigned short* Hseg = H + (size_t)seg * T_TOK * INTERI;
#pragma unroll
    for (int i = 0; i < 2; ++i) {
        int rbase = m0 + wm + i * 16 + quad * 4;
#pragma unroll
        for (int r = 0; r < 4; ++r) {
            int row = rbase + r;
            if (row >= n_e) continue;
            unsigned short* hrow = Hseg + (size_t)row * INTERI + n0 + wn + lrow;
#pragma unroll
            for (int j = 0; j < 4; ++j) {
                float v1 = acc1[i][j][r];
                float v3 = acc3[i][j][r];
                float hv = (v1 / (1.f + __expf(-v1))) * v3;   // silu(v1)*v3
                hrow[j * 16] = f2b(hv);
            }
        }
    }
}

// ---------- GEMM2: y += w * (H W2^T), tile 64m x 128n, BK=64, XCD-affine ----------
__global__ __launch_bounds__(256, 4) void gemm2_kernel(
    const unsigned short* __restrict__ H,
    const unsigned short* __restrict__ w2b,
    const unsigned short* __restrict__ ws2b,
    const int* __restrict__ counts,
    const int* __restrict__ lst,
    const float* __restrict__ lstw,
    float* __restrict__ y)
{
    int b = blockIdx.x;
    int seg, mt, nt;
    if (b < 4096) {
        int xcd = b & 7, slot = b >> 3;
        seg = xcd + 8 * (slot >> 8);
        int tile = slot & 255;
        nt = tile & 7; mt = tile >> 3;    // mt 0..31, nt 0..7
    } else {
        seg = NEXP;
        int tile = b - 4096;
        nt = tile & 7; mt = tile >> 3;
    }
    const int n_e = (seg == NEXP) ? T_TOK : counts[seg];
    const int m0  = mt * 64;
    if (m0 >= n_e) return;
    const int n0  = nt * 128;

    const unsigned short* w2p  = (seg == NEXP) ? ws2b : w2b + (size_t)seg * DIMD * INTERI;
    const unsigned short* Hseg = H + (size_t)seg * T_TOK * INTERI;

    __shared__ __align__(16) unsigned short lA[2][64][32];    // 8 KB
    __shared__ __align__(16) unsigned short lB[2][128][32];   // 16 KB

    const int tid  = threadIdx.x;
    const int wave = tid >> 6;
    const int lane = tid & 63;
    const int r4   = tid >> 2;
    const int skg  = (tid & 3) * 8;

    int ra = m0 + r4; if (ra > n_e - 1) ra = n_e - 1;
    const unsigned short* gA  = Hseg + (size_t)ra * INTERI + skg;
    const unsigned short* gB0 = w2p + (size_t)(n0 + r4) * INTERI + skg;
    const unsigned short* gB1 = w2p + (size_t)(n0 + r4 + 64) * INTERI + skg;

    const int wb = wave * 512;

    f32x4 acc[2][4];
    const f32x4 zero = {0.f, 0.f, 0.f, 0.f};
#pragma unroll
    for (int i = 0; i < 2; ++i)
#pragma unroll
        for (int j = 0; j < 4; ++j) acc[i][j] = zero;

    const int wm   = (wave & 1) * 32;
    const int wn   = (wave >> 1) * 64;
    const int quad = lane >> 4;
    const int lrow = lane & 15;

    for (int k0 = 0; k0 < INTERI; k0 += 64) {
#pragma unroll
        for (int kk = 0; kk < 2; ++kk) {
            cp16(gA  + k0 + kk * 32, &lA[kk][0][0]  + wb);
            cp16(gB0 + k0 + kk * 32, &lB[kk][0][0]  + wb);
            cp16(gB1 + k0 + kk * 32, &lB[kk][64][0] + wb);
        }
        __syncthreads();
#pragma unroll
        for (int kk = 0; kk < 2; ++kk) {
            bf16x8 a[2], bv[4];
#pragma unroll
            for (int t = 0; t < 2; ++t)
                a[t] = *(const bf16x8*)&lA[kk][wm + t * 16 + lrow][quad * 8];
#pragma unroll
            for (int t = 0; t < 4; ++t)
                bv[t] = *(const bf16x8*)&lB[kk][wn + t * 16 + lrow][quad * 8];
#pragma unroll
            for (int i = 0; i < 2; ++i)
#pragma unroll
                for (int j = 0; j < 4; ++j)
                    acc[i][j] = __builtin_amdgcn_mfma_f32_16x16x32_bf16(a[i], bv[j], acc[i][j], 0, 0, 0);
        }
        __syncthreads();
    }

#pragma unroll
    for (int i = 0; i < 2; ++i) {
        int rbase = m0 + wm + i * 16 + quad * 4;
#pragma unroll
        for (int r = 0; r < 4; ++r) {
            int row = rbase + r;
            if (row >= n_e) continue;
            int tok; float wt;
            if (seg == NEXP) { tok = row; wt = 1.f; }
            else { tok = lst[seg * T_TOK + row]; wt = lstw[seg * T_TOK + row]; }
            float* yrow = y + (size_t)tok * DIMD + n0 + wn + lrow;
#pragma unroll
            for (int j = 0; j < 4; ++j)
                atomicAdd(&yrow[j * 16], wt * acc[i][j][r]);
        }
    }
}

// ---------- launcher ----------
extern "C" void kernel_launch(void* const* d_in, const int* in_sizes, int n_in,
                              void* d_out, int out_size, void* d_ws, size_t ws_size,
                              hipStream_t stream)
{
    const float* x   = (const float*)d_in[0];
    const float* gw  = (const float*)d_in[1];
    const float* gb  = (const float*)d_in[2];
    const float* w1  = (const float*)d_in[3];
    const float* w2  = (const float*)d_in[4];
    const float* w3  = (const float*)d_in[5];
    const float* ws1 = (const float*)d_in[6];
    const float* ws2 = (const float*)d_in[7];
    const float* ws3 = (const float*)d_in[8];

    char* base = (char*)d_ws;
    size_t off = 0;
    auto alloc = [&](size_t bytes) {
        char* q = base + off; off += (bytes + 255) & ~(size_t)255; return q;
    };
    unsigned short* xb   = (unsigned short*)alloc((size_t)T_TOK * DIMD * 2);
    unsigned short* w1b  = (unsigned short*)alloc((size_t)NEXP * INTERI * DIMD * 2);
    unsigned short* w3b  = (unsigned short*)alloc((size_t)NEXP * INTERI * DIMD * 2);
    unsigned short* w2b  = (unsigned short*)alloc((size_t)NEXP * DIMD * INTERI * 2);
    unsigned short* ws1b = (unsigned short*)alloc((size_t)INTERI * DIMD * 2);
    unsigned short* ws3b = (unsigned short*)alloc((size_t)INTERI * DIMD * 2);
    unsigned short* ws2b = (unsigned short*)alloc((size_t)DIMD * INTERI * 2);
    unsigned short* Hb   = (unsigned short*)alloc((size_t)NSEG * T_TOK * INTERI * 2);
    int*            cnts = (int*)alloc(NEXP * 4);
    int*            lstp = (int*)alloc((size_t)NEXP * T_TOK * 4);
    float*          lstw = (float*)alloc((size_t)NEXP * T_TOK * 4);
    unsigned*       selp = (unsigned*)alloc((size_t)T_TOK * 4);
    float4*         selw = (float4*)alloc((size_t)T_TOK * 16);

    hipMemsetAsync(d_out, 0, (size_t)T_TOK * DIMD * 4, stream);

    cvt_all_kernel<<<28160, 256, 0, stream>>>(x, w1, w3, w2, ws1, ws3, ws2,
                                              xb, w1b, w3b, w2b, ws1b, ws3b, ws2b);
    gate_score_kernel<<<T_TOK / 4, 256, 0, stream>>>(x, gw, gb, selp, selw);
    build_lists_kernel<<<NEXP, 256, 0, stream>>>(selp, selw, cnts, lstp, lstw);
    gemm1_kernel<<<2176, 256, 0, stream>>>(xb, w1b, w3b, ws1b, ws3b, cnts, lstp, Hb);
    gemm2_kernel<<<4352, 256, 0, stream>>>(Hb, w2b, ws2b, cnts, lstp, lstw, (float*)d_out);
}

// Round 7
// 257.920 us; speedup vs baseline: 2.6219x; 1.0549x over previous
//
#include <hip/hip_runtime.h>

#define T_TOK  2048
#define DIMD   1024
#define INTERI 512
#define NEXP   16
#define NSEG   17   // 16 routed + 1 shared (index 16)

typedef __bf16 bf16x8 __attribute__((ext_vector_type(8)));
typedef float  f32x4  __attribute__((ext_vector_type(4)));

// ---------- helpers ----------
__device__ __forceinline__ unsigned short f2b(float f) {
    union { float f; unsigned int u; } c; c.f = f;
    unsigned int u = c.u;
    unsigned int r = (u + 0x7FFFu + ((u >> 16) & 1u)) >> 16;  // RNE
    return (unsigned short)r;
}

__device__ __forceinline__ void cp16(const unsigned short* g, unsigned short* l) {
    // direct global->LDS, 16B per lane; LDS dest = wave-uniform base + lane*16
    __builtin_amdgcn_global_load_lds(
        (const __attribute__((address_space(1))) unsigned int*)g,
        (__attribute__((address_space(3))) unsigned int*)l,
        16, 0, 0);
}

// ---------- fp32 -> bf16 conversion, all 7 tensors in one launch ----------
__global__ __launch_bounds__(256) void cvt_all_kernel(
    const float* __restrict__ x,  const float* __restrict__ w1,
    const float* __restrict__ w3, const float* __restrict__ w2,
    const float* __restrict__ ws1, const float* __restrict__ ws3,
    const float* __restrict__ ws2,
    unsigned short* __restrict__ xb,  unsigned short* __restrict__ w1b,
    unsigned short* __restrict__ w3b, unsigned short* __restrict__ w2b,
    unsigned short* __restrict__ ws1b, unsigned short* __restrict__ ws3b,
    unsigned short* __restrict__ ws2b)
{
    int g = blockIdx.x * 256 + threadIdx.x;
    const float* s; unsigned short* d; int i;
    if      (g < 524288)  { s = x;   d = xb;   i = g; }
    else if (g < 2621440) { s = w1;  d = w1b;  i = g - 524288; }
    else if (g < 4718592) { s = w3;  d = w3b;  i = g - 2621440; }
    else if (g < 6815744) { s = w2;  d = w2b;  i = g - 4718592; }
    else if (g < 6946816) { s = ws1; d = ws1b; i = g - 6815744; }
    else if (g < 7077888) { s = ws3; d = ws3b; i = g - 6946816; }
    else                  { s = ws2; d = ws2b; i = g - 7077888; }
    float4 v = ((const float4*)s)[i];
    ushort4 o;
    o.x = f2b(v.x); o.y = f2b(v.y); o.z = f2b(v.z); o.w = f2b(v.w);
    ((ushort4*)d)[i] = o;
}

// ---------- gate phase 1: scores + top-k selection, NO atomics ----------
__global__ __launch_bounds__(256) void gate_score_kernel(
    const float* __restrict__ x, const float* __restrict__ gw,
    const float* __restrict__ gb,
    unsigned* __restrict__ sel, float4* __restrict__ selw)
{
    int tok  = blockIdx.x * 4 + (threadIdx.x >> 6);   // one wave per token
    int lane = threadIdx.x & 63;
    const float* xp = x + (size_t)tok * DIMD;
    float xv[16];
#pragma unroll
    for (int j = 0; j < 16; ++j) xv[j] = xp[j * 64 + lane];

    float sc[16];
#pragma unroll
    for (int e = 0; e < 16; ++e) {
        const float* gwe = gw + e * DIMD;
        float p0 = 0.f, p1 = 0.f;
#pragma unroll
        for (int j = 0; j < 16; j += 2) {
            p0 += xv[j]     * gwe[j * 64 + lane];
            p1 += xv[j + 1] * gwe[(j + 1) * 64 + lane];
        }
        float p = p0 + p1;
#pragma unroll
        for (int o = 32; o; o >>= 1) p += __shfl_xor(p, o, 64);
        sc[e] = p;
    }
    if (lane != 0) return;

    float orig[16], s[16];
#pragma unroll
    for (int e = 0; e < 16; ++e) {
        orig[e] = 1.f / (1.f + expf(-sc[e]));
        s[e] = orig[e] + gb[e];
    }
    float gmax[4];
#pragma unroll
    for (int g = 0; g < 4; ++g) {
        float m = s[4 * g];
        for (int j = 1; j < 4; ++j) m = fmaxf(m, s[4 * g + j]);
        gmax[g] = m;
    }
    int g0 = 0;
    for (int g = 1; g < 4; ++g) if (gmax[g] > gmax[g0]) g0 = g;
    int g1 = -1;
    for (int g = 0; g < 4; ++g) { if (g == g0) continue; if (g1 < 0 || gmax[g] > gmax[g1]) g1 = g; }
    unsigned keep = (0xFu << (4 * g0)) | (0xFu << (4 * g1));
    unsigned used = 0;
    unsigned pk = 0;
    float w4[4];
    for (int j = 0; j < 4; ++j) {
        int best = -1;
        for (int e = 0; e < 16; ++e) {
            if (!((keep >> e) & 1u) || ((used >> e) & 1u)) continue;
            if (best < 0 || s[e] > s[best]) best = e;
        }
        used |= 1u << best;
        pk |= ((unsigned)best) << (4 * j);
        w4[j] = orig[best];
    }
    sel[tok] = pk;
    selw[tok] = make_float4(w4[0], w4[1], w4[2], w4[3]);
}

// ---------- gate phase 2: build per-expert token lists, NO atomics ----------
// lst entry packs token (low 16) | slot index (bits 16..17).
__global__ __launch_bounds__(256) void build_lists_kernel(
    const unsigned* __restrict__ sel, const float4* __restrict__ selw,
    int* __restrict__ counts, int* __restrict__ lst, float* __restrict__ lstw)
{
    const int e    = blockIdx.x;
    const int tid  = threadIdx.x;
    const int wave = tid >> 6;
    const int lane = tid & 63;

    __shared__ int wsum[4];
    __shared__ int basev;
    if (tid == 0) basev = 0;
    __syncthreads();

    for (int c = 0; c < T_TOK / 256; ++c) {
        int t = c * 256 + tid;
        unsigned s = sel[t];
        int match = -1;
#pragma unroll
        for (int j = 0; j < 4; ++j)
            if (((s >> (4 * j)) & 15u) == (unsigned)e) match = j;
        unsigned long long m = __ballot(match >= 0);
        int wpre = __popcll(m & ((1ull << lane) - 1ull));
        if (lane == 0) wsum[wave] = __popcll(m);
        __syncthreads();
        int pre = basev;
        for (int wv = 0; wv < wave; ++wv) pre += wsum[wv];
        if (match >= 0) {
            int pos = pre + wpre;
            lst [e * T_TOK + pos] = t | (match << 16);
            const float* wp = (const float*)&selw[t];
            lstw[e * T_TOK + pos] = wp[match];
        }
        __syncthreads();
        if (tid == 0) basev += wsum[0] + wsum[1] + wsum[2] + wsum[3];
        __syncthreads();
    }
    if (tid == 0) counts[e] = basev;
}

// ---------- GEMM1: H = silu(X W1^T) * (X W3^T) ----------
// Tile 64m x 128n, BK=64. XCD-affine flattened grid (expert s -> XCD s%8).
__global__ __launch_bounds__(256, 4) void gemm1_kernel(
    const unsigned short* __restrict__ xb,
    const unsigned short* __restrict__ w1b,
    const unsigned short* __restrict__ w3b,
    const unsigned short* __restrict__ ws1b,
    const unsigned short* __restrict__ ws3b,
    const int* __restrict__ counts,
    const int* __restrict__ lst,
    unsigned short* __restrict__ H)
{
    int b = blockIdx.x;
    int seg, mt, nt;
    if (b < 2048) {
        int xcd = b & 7, slot = b >> 3;
        seg = xcd + 8 * (slot >> 7);
        int tile = slot & 127;
        nt = tile & 3; mt = tile >> 2;
    } else {
        seg = NEXP;
        int tile = b - 2048;
        nt = tile & 3; mt = tile >> 2;
    }
    const int n_e = (seg == NEXP) ? T_TOK : counts[seg];
    const int m0  = mt * 64;
    if (m0 >= n_e) return;
    const int n0  = nt * 128;

    const unsigned short* w1p = (seg == NEXP) ? ws1b : w1b + (size_t)seg * INTERI * DIMD;
    const unsigned short* w3p = (seg == NEXP) ? ws3b : w3b + (size_t)seg * INTERI * DIMD;
    const int* lste = lst + seg * T_TOK;

    __shared__ __align__(16) unsigned short lA [2][64][32];    // 8 KB
    __shared__ __align__(16) unsigned short lB1[2][128][32];   // 16 KB
    __shared__ __align__(16) unsigned short lB3[2][128][32];   // 16 KB

    const int tid  = threadIdx.x;
    const int wave = tid >> 6;
    const int lane = tid & 63;
    const int r4   = tid >> 2;
    const int skg  = (tid & 3) * 8;

    int ra = m0 + r4; if (ra > n_e - 1) ra = n_e - 1;
    int tok = (seg == NEXP) ? ra : (lste[ra] & 0xFFFF);
    const unsigned short* gA  = xb  + (size_t)tok * DIMD + skg;
    const unsigned short* gB1a = w1p + (size_t)(n0 + r4) * DIMD + skg;
    const unsigned short* gB1b = w1p + (size_t)(n0 + r4 + 64) * DIMD + skg;
    const unsigned short* gB3a = w3p + (size_t)(n0 + r4) * DIMD + skg;
    const unsigned short* gB3b = w3p + (size_t)(n0 + r4 + 64) * DIMD + skg;

    const int wb = wave * 512;

    f32x4 acc1[2][4], acc3[2][4];
    const f32x4 zero = {0.f, 0.f, 0.f, 0.f};
#pragma unroll
    for (int i = 0; i < 2; ++i)
#pragma unroll
        for (int j = 0; j < 4; ++j) { acc1[i][j] = zero; acc3[i][j] = zero; }

    const int wm   = (wave & 1) * 32;
    const int wn   = (wave >> 1) * 64;
    const int quad = lane >> 4;
    const int lrow = lane & 15;

    for (int k0 = 0; k0 < DIMD; k0 += 64) {
#pragma unroll
        for (int kk = 0; kk < 2; ++kk) {
            cp16(gA   + k0 + kk * 32, &lA [kk][0][0]  + wb);
            cp16(gB1a + k0 + kk * 32, &lB1[kk][0][0]  + wb);
            cp16(gB1b + k0 + kk * 32, &lB1[kk][64][0] + wb);
            cp16(gB3a + k0 + kk * 32, &lB3[kk][0][0]  + wb);
            cp16(gB3b + k0 + kk * 32, &lB3[kk][64][0] + wb);
        }
        __syncthreads();
#pragma unroll
        for (int kk = 0; kk < 2; ++kk) {
            bf16x8 a[2], b1[4], b3[4];
#pragma unroll
            for (int t = 0; t < 2; ++t)
                a[t] = *(const bf16x8*)&lA[kk][wm + t * 16 + lrow][quad * 8];
#pragma unroll
            for (int t = 0; t < 4; ++t) {
                b1[t] = *(const bf16x8*)&lB1[kk][wn + t * 16 + lrow][quad * 8];
                b3[t] = *(const bf16x8*)&lB3[kk][wn + t * 16 + lrow][quad * 8];
            }
#pragma unroll
            for (int i = 0; i < 2; ++i)
#pragma unroll
                for (int j = 0; j < 4; ++j) {
                    acc1[i][j] = __builtin_amdgcn_mfma_f32_16x16x32_bf16(a[i], b1[j], acc1[i][j], 0, 0, 0);
                    acc3[i][j] = __builtin_amdgcn_mfma_f32_16x16x32_bf16(a[i], b3[j], acc3[i][j], 0, 0, 0);
                }
        }
        __syncthreads();
    }

    unsigned short* Hseg = H + (size_t)seg * T_TOK * INTERI;
#pragma unroll
    for (int i = 0; i < 2; ++i) {
        int rbase = m0 + wm + i * 16 + quad * 4;
#pragma unroll
        for (int r = 0; r < 4; ++r) {
            int row = rbase + r;
            if (row >= n_e) continue;
            unsigned short* hrow = Hseg + (size_t)row * INTERI + n0 + wn + lrow;
#pragma unroll
            for (int j = 0; j < 4; ++j) {
                float v1 = acc1[i][j][r];
                float v3 = acc3[i][j][r];
                float hv = (v1 / (1.f + __expf(-v1))) * v3;   // silu(v1)*v3
                hrow[j * 16] = f2b(hv);
            }
        }
    }
}

// ---------- GEMM2: P[slot] = w * (H W2^T)  — atomic-free partials ----------
// P layout: [5][T_TOK][DIMD] fp32; every (slot,token,col) written exactly once.
__global__ __launch_bounds__(256, 4) void gemm2_kernel(
    const unsigned short* __restrict__ H,
    const unsigned short* __restrict__ w2b,
    const unsigned short* __restrict__ ws2b,
    const int* __restrict__ counts,
    const int* __restrict__ lst,
    const float* __restrict__ lstw,
    float* __restrict__ P)
{
    int b = blockIdx.x;
    int seg, mt, nt;
    if (b < 4096) {
        int xcd = b & 7, slot = b >> 3;
        seg = xcd + 8 * (slot >> 8);
        int tile = slot & 255;
        nt = tile & 7; mt = tile >> 3;
    } else {
        seg = NEXP;
        int tile = b - 4096;
        nt = tile & 7; mt = tile >> 3;
    }
    const int n_e = (seg == NEXP) ? T_TOK : counts[seg];
    const int m0  = mt * 64;
    if (m0 >= n_e) return;
    const int n0  = nt * 128;

    const unsigned short* w2p  = (seg == NEXP) ? ws2b : w2b + (size_t)seg * DIMD * INTERI;
    const unsigned short* Hseg = H + (size_t)seg * T_TOK * INTERI;

    __shared__ __align__(16) unsigned short lA[2][64][32];    // 8 KB
    __shared__ __align__(16) unsigned short lB[2][128][32];   // 16 KB

    const int tid  = threadIdx.x;
    const int wave = tid >> 6;
    const int lane = tid & 63;
    const int r4   = tid >> 2;
    const int skg  = (tid & 3) * 8;

    int ra = m0 + r4; if (ra > n_e - 1) ra = n_e - 1;
    const unsigned short* gA  = Hseg + (size_t)ra * INTERI + skg;
    const unsigned short* gB0 = w2p + (size_t)(n0 + r4) * INTERI + skg;
    const unsigned short* gB1 = w2p + (size_t)(n0 + r4 + 64) * INTERI + skg;

    const int wb = wave * 512;

    f32x4 acc[2][4];
    const f32x4 zero = {0.f, 0.f, 0.f, 0.f};
#pragma unroll
    for (int i = 0; i < 2; ++i)
#pragma unroll
        for (int j = 0; j < 4; ++j) acc[i][j] = zero;

    const int wm   = (wave & 1) * 32;
    const int wn   = (wave >> 1) * 64;
    const int quad = lane >> 4;
    const int lrow = lane & 15;

    for (int k0 = 0; k0 < INTERI; k0 += 64) {
#pragma unroll
        for (int kk = 0; kk < 2; ++kk) {
            cp16(gA  + k0 + kk * 32, &lA[kk][0][0]  + wb);
            cp16(gB0 + k0 + kk * 32, &lB[kk][0][0]  + wb);
            cp16(gB1 + k0 + kk * 32, &lB[kk][64][0] + wb);
        }
        __syncthreads();
#pragma unroll
        for (int kk = 0; kk < 2; ++kk) {
            bf16x8 a[2], bv[4];
#pragma unroll
            for (int t = 0; t < 2; ++t)
                a[t] = *(const bf16x8*)&lA[kk][wm + t * 16 + lrow][quad * 8];
#pragma unroll
            for (int t = 0; t < 4; ++t)
                bv[t] = *(const bf16x8*)&lB[kk][wn + t * 16 + lrow][quad * 8];
#pragma unroll
            for (int i = 0; i < 2; ++i)
#pragma unroll
                for (int j = 0; j < 4; ++j)
                    acc[i][j] = __builtin_amdgcn_mfma_f32_16x16x32_bf16(a[i], bv[j], acc[i][j], 0, 0, 0);
        }
        __syncthreads();
    }

#pragma unroll
    for (int i = 0; i < 2; ++i) {
        int rbase = m0 + wm + i * 16 + quad * 4;
#pragma unroll
        for (int r = 0; r < 4; ++r) {
            int row = rbase + r;
            if (row >= n_e) continue;
            int tok, slot; float wt;
            if (seg == NEXP) { tok = row; slot = 4; wt = 1.f; }
            else {
                int ent = lst[seg * T_TOK + row];
                tok = ent & 0xFFFF; slot = ent >> 16;
                wt = lstw[seg * T_TOK + row];
            }
            float* prow = P + ((size_t)slot * T_TOK + tok) * DIMD + n0 + wn + lrow;
#pragma unroll
            for (int j = 0; j < 4; ++j)
                prow[j * 16] = wt * acc[i][j][r];
        }
    }
}

// ---------- combine: y = P0+P1+P2+P3+P4 ----------
__global__ __launch_bounds__(256) void combine_kernel(
    const float4* __restrict__ P, float4* __restrict__ y)
{
    const int i = blockIdx.x * 256 + threadIdx.x;   // over T*D/4
    const size_t plane = (size_t)T_TOK * DIMD / 4;
    float4 a = P[i];
    float4 b = P[plane + i];
    float4 c = P[2 * plane + i];
    float4 d = P[3 * plane + i];
    float4 e = P[4 * plane + i];
    float4 o;
    o.x = a.x + b.x + c.x + d.x + e.x;
    o.y = a.y + b.y + c.y + d.y + e.y;
    o.z = a.z + b.z + c.z + d.z + e.z;
    o.w = a.w + b.w + c.w + d.w + e.w;
    y[i] = o;
}

// ---------- launcher ----------
extern "C" void kernel_launch(void* const* d_in, const int* in_sizes, int n_in,
                              void* d_out, int out_size, void* d_ws, size_t ws_size,
                              hipStream_t stream)
{
    const float* x   = (const float*)d_in[0];
    const float* gw  = (const float*)d_in[1];
    const float* gb  = (const float*)d_in[2];
    const float* w1  = (const float*)d_in[3];
    const float* w2  = (const float*)d_in[4];
    const float* w3  = (const float*)d_in[5];
    const float* ws1 = (const float*)d_in[6];
    const float* ws2 = (const float*)d_in[7];
    const float* ws3 = (const float*)d_in[8];

    char* base = (char*)d_ws;
    size_t off = 0;
    auto alloc = [&](size_t bytes) {
        char* q = base + off; off += (bytes + 255) & ~(size_t)255; return q;
    };
    unsigned short* xb   = (unsigned short*)alloc((size_t)T_TOK * DIMD * 2);
    unsigned short* w1b  = (unsigned short*)alloc((size_t)NEXP * INTERI * DIMD * 2);
    unsigned short* w3b  = (unsigned short*)alloc((size_t)NEXP * INTERI * DIMD * 2);
    unsigned short* w2b  = (unsigned short*)alloc((size_t)NEXP * DIMD * INTERI * 2);
    unsigned short* ws1b = (unsigned short*)alloc((size_t)INTERI * DIMD * 2);
    unsigned short* ws3b = (unsigned short*)alloc((size_t)INTERI * DIMD * 2);
    unsigned short* ws2b = (unsigned short*)alloc((size_t)DIMD * INTERI * 2);
    unsigned short* Hb   = (unsigned short*)alloc((size_t)NSEG * T_TOK * INTERI * 2);
    int*            cnts = (int*)alloc(NEXP * 4);
    int*            lstp = (int*)alloc((size_t)NEXP * T_TOK * 4);
    float*          lstw = (float*)alloc((size_t)NEXP * T_TOK * 4);
    unsigned*       selp = (unsigned*)alloc((size_t)T_TOK * 4);
    float4*         selw = (float4*)alloc((size_t)T_TOK * 16);
    float*          Pb   = (float*)alloc((size_t)5 * T_TOK * DIMD * 4);

    cvt_all_kernel<<<28160, 256, 0, stream>>>(x, w1, w3, w2, ws1, ws3, ws2,
                                              xb, w1b, w3b, w2b, ws1b, ws3b, ws2b);
    gate_score_kernel<<<T_TOK / 4, 256, 0, stream>>>(x, gw, gb, selp, selw);
    build_lists_kernel<<<NEXP, 256, 0, stream>>>(selp, selw, cnts, lstp, lstw);
    gemm1_kernel<<<2176, 256, 0, stream>>>(xb, w1b, w3b, ws1b, ws3b, cnts, lstp, Hb);
    gemm2_kernel<<<4352, 256, 0, stream>>>(Hb, w2b, ws2b, cnts, lstp, lstw, Pb);
    combine_kernel<<<(T_TOK * DIMD / 4) / 256, 256, 0, stream>>>((const float4*)Pb, (float4*)d_out);
}

// Round 8
// 257.830 us; speedup vs baseline: 2.6228x; 1.0003x over previous
//
#include <hip/hip_runtime.h>

#define T_TOK  2048
#define DIMD   1024
#define INTERI 512
#define NEXP   16
#define NSEG   17   // 16 routed + 1 shared (index 16)

typedef __bf16 bf16x8 __attribute__((ext_vector_type(8)));
typedef float  f32x4  __attribute__((ext_vector_type(4)));

// ---------- helpers ----------
__device__ __forceinline__ unsigned short f2b(float f) {
    union { float f; unsigned int u; } c; c.f = f;
    unsigned int u = c.u;
    unsigned int r = (u + 0x7FFFu + ((u >> 16) & 1u)) >> 16;  // RNE
    return (unsigned short)r;
}

// raw barrier: waits only LDS ops, leaves global loads in flight (the whole point)
__device__ __forceinline__ void lds_barrier() {
    asm volatile("s_waitcnt lgkmcnt(0)" ::: "memory");
    __builtin_amdgcn_s_barrier();
}

// ---------- fp32 -> bf16 conversion, all 7 tensors in one launch ----------
__global__ __launch_bounds__(256) void cvt_all_kernel(
    const float* __restrict__ x,  const float* __restrict__ w1,
    const float* __restrict__ w3, const float* __restrict__ w2,
    const float* __restrict__ ws1, const float* __restrict__ ws3,
    const float* __restrict__ ws2,
    unsigned short* __restrict__ xb,  unsigned short* __restrict__ w1b,
    unsigned short* __restrict__ w3b, unsigned short* __restrict__ w2b,
    unsigned short* __restrict__ ws1b, unsigned short* __restrict__ ws3b,
    unsigned short* __restrict__ ws2b)
{
    int g = blockIdx.x * 256 + threadIdx.x;
    const float* s; unsigned short* d; int i;
    if      (g < 524288)  { s = x;   d = xb;   i = g; }
    else if (g < 2621440) { s = w1;  d = w1b;  i = g - 524288; }
    else if (g < 4718592) { s = w3;  d = w3b;  i = g - 2621440; }
    else if (g < 6815744) { s = w2;  d = w2b;  i = g - 4718592; }
    else if (g < 6946816) { s = ws1; d = ws1b; i = g - 6815744; }
    else if (g < 7077888) { s = ws3; d = ws3b; i = g - 6946816; }
    else                  { s = ws2; d = ws2b; i = g - 7077888; }
    float4 v = ((const float4*)s)[i];
    ushort4 o;
    o.x = f2b(v.x); o.y = f2b(v.y); o.z = f2b(v.z); o.w = f2b(v.w);
    ((ushort4*)d)[i] = o;
}

// ---------- gate phase 1: scores + top-k selection, NO atomics ----------
__global__ __launch_bounds__(256) void gate_score_kernel(
    const float* __restrict__ x, const float* __restrict__ gw,
    const float* __restrict__ gb,
    unsigned* __restrict__ sel, float4* __restrict__ selw)
{
    int tok  = blockIdx.x * 4 + (threadIdx.x >> 6);   // one wave per token
    int lane = threadIdx.x & 63;
    const float* xp = x + (size_t)tok * DIMD;
    float xv[16];
#pragma unroll
    for (int j = 0; j < 16; ++j) xv[j] = xp[j * 64 + lane];

    float sc[16];
#pragma unroll
    for (int e = 0; e < 16; ++e) {
        const float* gwe = gw + e * DIMD;
        float p0 = 0.f, p1 = 0.f;
#pragma unroll
        for (int j = 0; j < 16; j += 2) {
            p0 += xv[j]     * gwe[j * 64 + lane];
            p1 += xv[j + 1] * gwe[(j + 1) * 64 + lane];
        }
        float p = p0 + p1;
#pragma unroll
        for (int o = 32; o; o >>= 1) p += __shfl_xor(p, o, 64);
        sc[e] = p;
    }
    if (lane != 0) return;

    float orig[16], s[16];
#pragma unroll
    for (int e = 0; e < 16; ++e) {
        orig[e] = 1.f / (1.f + expf(-sc[e]));
        s[e] = orig[e] + gb[e];
    }
    float gmax[4];
#pragma unroll
    for (int g = 0; g < 4; ++g) {
        float m = s[4 * g];
        for (int j = 1; j < 4; ++j) m = fmaxf(m, s[4 * g + j]);
        gmax[g] = m;
    }
    int g0 = 0;
    for (int g = 1; g < 4; ++g) if (gmax[g] > gmax[g0]) g0 = g;
    int g1 = -1;
    for (int g = 0; g < 4; ++g) { if (g == g0) continue; if (g1 < 0 || gmax[g] > gmax[g1]) g1 = g; }
    unsigned keep = (0xFu << (4 * g0)) | (0xFu << (4 * g1));
    unsigned used = 0;
    unsigned pk = 0;
    float w4[4];
    for (int j = 0; j < 4; ++j) {
        int best = -1;
        for (int e = 0; e < 16; ++e) {
            if (!((keep >> e) & 1u) || ((used >> e) & 1u)) continue;
            if (best < 0 || s[e] > s[best]) best = e;
        }
        used |= 1u << best;
        pk |= ((unsigned)best) << (4 * j);
        w4[j] = orig[best];
    }
    sel[tok] = pk;
    selw[tok] = make_float4(w4[0], w4[1], w4[2], w4[3]);
}

// ---------- gate phase 2: build per-expert token lists, NO atomics ----------
// lst entry packs token (low 16) | slot index (bits 16..17).
__global__ __launch_bounds__(256) void build_lists_kernel(
    const unsigned* __restrict__ sel, const float4* __restrict__ selw,
    int* __restrict__ counts, int* __restrict__ lst, float* __restrict__ lstw)
{
    const int e    = blockIdx.x;
    const int tid  = threadIdx.x;
    const int wave = tid >> 6;
    const int lane = tid & 63;

    __shared__ int wsum[4];
    __shared__ int basev;
    if (tid == 0) basev = 0;
    __syncthreads();

    for (int c = 0; c < T_TOK / 256; ++c) {
        int t = c * 256 + tid;
        unsigned s = sel[t];
        int match = -1;
#pragma unroll
        for (int j = 0; j < 4; ++j)
            if (((s >> (4 * j)) & 15u) == (unsigned)e) match = j;
        unsigned long long m = __ballot(match >= 0);
        int wpre = __popcll(m & ((1ull << lane) - 1ull));
        if (lane == 0) wsum[wave] = __popcll(m);
        __syncthreads();
        int pre = basev;
        for (int wv = 0; wv < wave; ++wv) pre += wsum[wv];
        if (match >= 0) {
            int pos = pre + wpre;
            lst [e * T_TOK + pos] = t | (match << 16);
            const float* wp = (const float*)&selw[t];
            lstw[e * T_TOK + pos] = wp[match];
        }
        __syncthreads();
        if (tid == 0) basev += wsum[0] + wsum[1] + wsum[2] + wsum[3];
        __syncthreads();
    }
    if (tid == 0) counts[e] = basev;
}

// ---------- GEMM1: H = silu(X W1^T) * (X W3^T) ----------
// Tile 64m x 128n, BK=64. XCD-affine grid (expert s -> XCD s%8).
// Software-pipelined: global->VGPR prefetch crosses raw lgkm-only barriers,
// so next tile's loads stay in flight during MFMA (no vmcnt(0) drain).
__global__ __launch_bounds__(256, 4) void gemm1_kernel(
    const unsigned short* __restrict__ xb,
    const unsigned short* __restrict__ w1b,
    const unsigned short* __restrict__ w3b,
    const unsigned short* __restrict__ ws1b,
    const unsigned short* __restrict__ ws3b,
    const int* __restrict__ counts,
    const int* __restrict__ lst,
    unsigned short* __restrict__ H)
{
    int b = blockIdx.x;
    int seg, mt, nt;
    if (b < 2048) {
        int xcd = b & 7, slot = b >> 3;
        seg = xcd + 8 * (slot >> 7);
        int tile = slot & 127;
        nt = tile & 3; mt = tile >> 2;
    } else {
        seg = NEXP;
        int tile = b - 2048;
        nt = tile & 3; mt = tile >> 2;
    }
    const int n_e = (seg == NEXP) ? T_TOK : counts[seg];
    const int m0  = mt * 64;
    if (m0 >= n_e) return;
    const int n0  = nt * 128;

    const unsigned short* w1p = (seg == NEXP) ? ws1b : w1b + (size_t)seg * INTERI * DIMD;
    const unsigned short* w3p = (seg == NEXP) ? ws3b : w3b + (size_t)seg * INTERI * DIMD;
    const int* lste = lst + seg * T_TOK;

    __shared__ __align__(16) unsigned short lA [2][64][32];    // 8 KB
    __shared__ __align__(16) unsigned short lB1[2][128][32];   // 16 KB
    __shared__ __align__(16) unsigned short lB3[2][128][32];   // 16 KB

    const int tid  = threadIdx.x;
    const int wave = tid >> 6;
    const int lane = tid & 63;
    const int r4   = tid >> 2;        // 0..63
    const int skg  = (tid & 3) * 8;   // elem offset in 32-col panel

    int ra = m0 + r4; if (ra > n_e - 1) ra = n_e - 1;
    int tok = (seg == NEXP) ? ra : (lste[ra] & 0xFFFF);
    const unsigned short* gA   = xb  + (size_t)tok * DIMD + skg;
    const unsigned short* gB1a = w1p + (size_t)(n0 + r4) * DIMD + skg;
    const unsigned short* gB1b = w1p + (size_t)(n0 + r4 + 64) * DIMD + skg;
    const unsigned short* gB3a = w3p + (size_t)(n0 + r4) * DIMD + skg;
    const unsigned short* gB3b = w3p + (size_t)(n0 + r4 + 64) * DIMD + skg;

    bf16x8 pa[2], pb1a[2], pb1b[2], pb3a[2], pb3b[2];

#define G1LOAD(k0) do { _Pragma("unroll") for (int kk = 0; kk < 2; ++kk) { \
    pa  [kk] = *(const bf16x8*)(gA   + (k0) + kk * 32); \
    pb1a[kk] = *(const bf16x8*)(gB1a + (k0) + kk * 32); \
    pb1b[kk] = *(const bf16x8*)(gB1b + (k0) + kk * 32); \
    pb3a[kk] = *(const bf16x8*)(gB3a + (k0) + kk * 32); \
    pb3b[kk] = *(const bf16x8*)(gB3b + (k0) + kk * 32); } } while (0)

#define G1STORE() do { _Pragma("unroll") for (int kk = 0; kk < 2; ++kk) { \
    *(bf16x8*)&lA [kk][r4][skg]      = pa  [kk]; \
    *(bf16x8*)&lB1[kk][r4][skg]      = pb1a[kk]; \
    *(bf16x8*)&lB1[kk][64 + r4][skg] = pb1b[kk]; \
    *(bf16x8*)&lB3[kk][r4][skg]      = pb3a[kk]; \
    *(bf16x8*)&lB3[kk][64 + r4][skg] = pb3b[kk]; } } while (0)

    f32x4 acc1[2][4], acc3[2][4];
    const f32x4 zero = {0.f, 0.f, 0.f, 0.f};
#pragma unroll
    for (int i = 0; i < 2; ++i)
#pragma unroll
        for (int j = 0; j < 4; ++j) { acc1[i][j] = zero; acc3[i][j] = zero; }

    const int wm   = (wave & 1) * 32;
    const int wn   = (wave >> 1) * 64;
    const int quad = lane >> 4;
    const int lrow = lane & 15;

    G1LOAD(0);
    const int NK = DIMD / 64;  // 16
    for (int it = 0; it < NK; ++it) {
        G1STORE();
        lds_barrier();                       // writes visible; loads stay in flight
        if (it + 1 < NK) G1LOAD((it + 1) * 64);
#pragma unroll
        for (int kk = 0; kk < 2; ++kk) {
            bf16x8 a[2], b1[4], b3[4];
#pragma unroll
            for (int t = 0; t < 2; ++t)
                a[t] = *(const bf16x8*)&lA[kk][wm + t * 16 + lrow][quad * 8];
#pragma unroll
            for (int t = 0; t < 4; ++t) {
                b1[t] = *(const bf16x8*)&lB1[kk][wn + t * 16 + lrow][quad * 8];
                b3[t] = *(const bf16x8*)&lB3[kk][wn + t * 16 + lrow][quad * 8];
            }
#pragma unroll
            for (int i = 0; i < 2; ++i)
#pragma unroll
                for (int j = 0; j < 4; ++j) {
                    acc1[i][j] = __builtin_amdgcn_mfma_f32_16x16x32_bf16(a[i], b1[j], acc1[i][j], 0, 0, 0);
                    acc3[i][j] = __builtin_amdgcn_mfma_f32_16x16x32_bf16(a[i], b3[j], acc3[i][j], 0, 0, 0);
                }
        }
        lds_barrier();                       // LDS reads done before next overwrite
    }
#undef G1LOAD
#undef G1STORE

    unsigned short* Hseg = H + (size_t)seg * T_TOK * INTERI;
#pragma unroll
    for (int i = 0; i < 2; ++i) {
        int rbase = m0 + wm + i * 16 + quad * 4;
#pragma unroll
        for (int r = 0; r < 4; ++r) {
            int row = rbase + r;
            if (row >= n_e) continue;
            unsigned short* hrow = Hseg + (size_t)row * INTERI + n0 + wn + lrow;
#pragma unroll
            for (int j = 0; j < 4; ++j) {
                float v1 = acc1[i][j][r];
                float v3 = acc3[i][j][r];
                float hv = (v1 / (1.f + __expf(-v1))) * v3;   // silu(v1)*v3
                hrow[j * 16] = f2b(hv);
            }
        }
    }
}

// ---------- GEMM2: P[slot] = w * (H W2^T), pipelined, atomic-free ----------
__global__ __launch_bounds__(256, 4) void gemm2_kernel(
    const unsigned short* __restrict__ H,
    const unsigned short* __restrict__ w2b,
    const unsigned short* __restrict__ ws2b,
    const int* __restrict__ counts,
    const int* __restrict__ lst,
    const float* __restrict__ lstw,
    float* __restrict__ P)
{
    int b = blockIdx.x;
    int seg, mt, nt;
    if (b < 4096) {
        int xcd = b & 7, slot = b >> 3;
        seg = xcd + 8 * (slot >> 8);
        int tile = slot & 255;
        nt = tile & 7; mt = tile >> 3;
    } else {
        seg = NEXP;
        int tile = b - 4096;
        nt = tile & 7; mt = tile >> 3;
    }
    const int n_e = (seg == NEXP) ? T_TOK : counts[seg];
    const int m0  = mt * 64;
    if (m0 >= n_e) return;
    const int n0  = nt * 128;

    const unsigned short* w2p  = (seg == NEXP) ? ws2b : w2b + (size_t)seg * DIMD * INTERI;
    const unsigned short* Hseg = H + (size_t)seg * T_TOK * INTERI;

    __shared__ __align__(16) unsigned short lA[2][64][32];    // 8 KB
    __shared__ __align__(16) unsigned short lB[2][128][32];   // 16 KB

    const int tid  = threadIdx.x;
    const int wave = tid >> 6;
    const int lane = tid & 63;
    const int r4   = tid >> 2;
    const int skg  = (tid & 3) * 8;

    int ra = m0 + r4; if (ra > n_e - 1) ra = n_e - 1;
    const unsigned short* gA  = Hseg + (size_t)ra * INTERI + skg;
    const unsigned short* gB0 = w2p + (size_t)(n0 + r4) * INTERI + skg;
    const unsigned short* gB1 = w2p + (size_t)(n0 + r4 + 64) * INTERI + skg;

    bf16x8 pa[2], pb0[2], pb1[2];

#define G2LOAD(k0) do { _Pragma("unroll") for (int kk = 0; kk < 2; ++kk) { \
    pa [kk] = *(const bf16x8*)(gA  + (k0) + kk * 32); \
    pb0[kk] = *(const bf16x8*)(gB0 + (k0) + kk * 32); \
    pb1[kk] = *(const bf16x8*)(gB1 + (k0) + kk * 32); } } while (0)

#define G2STORE() do { _Pragma("unroll") for (int kk = 0; kk < 2; ++kk) { \
    *(bf16x8*)&lA[kk][r4][skg]      = pa [kk]; \
    *(bf16x8*)&lB[kk][r4][skg]      = pb0[kk]; \
    *(bf16x8*)&lB[kk][64 + r4][skg] = pb1[kk]; } } while (0)

    f32x4 acc[2][4];
    const f32x4 zero = {0.f, 0.f, 0.f, 0.f};
#pragma unroll
    for (int i = 0; i < 2; ++i)
#pragma unroll
        for (int j = 0; j < 4; ++j) acc[i][j] = zero;

    const int wm   = (wave & 1) * 32;
    const int wn   = (wave >> 1) * 64;
    const int quad = lane >> 4;
    const int lrow = lane & 15;

    G2LOAD(0);
    const int NK = INTERI / 64;  // 8
    for (int it = 0; it < NK; ++it) {
        G2STORE();
        lds_barrier();
        if (it + 1 < NK) G2LOAD((it + 1) * 64);
#pragma unroll
        for (int kk = 0; kk < 2; ++kk) {
            bf16x8 a[2], bv[4];
#pragma unroll
            for (int t = 0; t < 2; ++t)
                a[t] = *(const bf16x8*)&lA[kk][wm + t * 16 + lrow][quad * 8];
#pragma unroll
            for (int t = 0; t < 4; ++t)
                bv[t] = *(const bf16x8*)&lB[kk][wn + t * 16 + lrow][quad * 8];
#pragma unroll
            for (int i = 0; i < 2; ++i)
#pragma unroll
                for (int j = 0; j < 4; ++j)
                    acc[i][j] = __builtin_amdgcn_mfma_f32_16x16x32_bf16(a[i], bv[j], acc[i][j], 0, 0, 0);
        }
        lds_barrier();
    }
#undef G2LOAD
#undef G2STORE

#pragma unroll
    for (int i = 0; i < 2; ++i) {
        int rbase = m0 + wm + i * 16 + quad * 4;
#pragma unroll
        for (int r = 0; r < 4; ++r) {
            int row = rbase + r;
            if (row >= n_e) continue;
            int tok, slot; float wt;
            if (seg == NEXP) { tok = row; slot = 4; wt = 1.f; }
            else {
                int ent = lst[seg * T_TOK + row];
                tok = ent & 0xFFFF; slot = ent >> 16;
                wt = lstw[seg * T_TOK + row];
            }
            float* prow = P + ((size_t)slot * T_TOK + tok) * DIMD + n0 + wn + lrow;
#pragma unroll
            for (int j = 0; j < 4; ++j)
                prow[j * 16] = wt * acc[i][j][r];
        }
    }
}

// ---------- combine: y = P0+P1+P2+P3+P4 ----------
__global__ __launch_bounds__(256) void combine_kernel(
    const float4* __restrict__ P, float4* __restrict__ y)
{
    const int i = blockIdx.x * 256 + threadIdx.x;   // over T*D/4
    const size_t plane = (size_t)T_TOK * DIMD / 4;
    float4 a = P[i];
    float4 b = P[plane + i];
    float4 c = P[2 * plane + i];
    float4 d = P[3 * plane + i];
    float4 e = P[4 * plane + i];
    float4 o;
    o.x = a.x + b.x + c.x + d.x + e.x;
    o.y = a.y + b.y + c.y + d.y + e.y;
    o.z = a.z + b.z + c.z + d.z + e.z;
    o.w = a.w + b.w + c.w + d.w + e.w;
    y[i] = o;
}

// ---------- launcher ----------
extern "C" void kernel_launch(void* const* d_in, const int* in_sizes, int n_in,
                              void* d_out, int out_size, void* d_ws, size_t ws_size,
                              hipStream_t stream)
{
    const float* x   = (const float*)d_in[0];
    const float* gw  = (const float*)d_in[1];
    const float* gb  = (const float*)d_in[2];
    const float* w1  = (const float*)d_in[3];
    const float* w2  = (const float*)d_in[4];
    const float* w3  = (const float*)d_in[5];
    const float* ws1 = (const float*)d_in[6];
    const float* ws2 = (const float*)d_in[7];
    const float* ws3 = (const float*)d_in[8];

    char* base = (char*)d_ws;
    size_t off = 0;
    auto alloc = [&](size_t bytes) {
        char* q = base + off; off += (bytes + 255) & ~(size_t)255; return q;
    };
    unsigned short* xb   = (unsigned short*)alloc((size_t)T_TOK * DIMD * 2);
    unsigned short* w1b  = (unsigned short*)alloc((size_t)NEXP * INTERI * DIMD * 2);
    unsigned short* w3b  = (unsigned short*)alloc((size_t)NEXP * INTERI * DIMD * 2);
    unsigned short* w2b  = (unsigned short*)alloc((size_t)NEXP * DIMD * INTERI * 2);
    unsigned short* ws1b = (unsigned short*)alloc((size_t)INTERI * DIMD * 2);
    unsigned short* ws3b = (unsigned short*)alloc((size_t)INTERI * DIMD * 2);
    unsigned short* ws2b = (unsigned short*)alloc((size_t)DIMD * INTERI * 2);
    unsigned short* Hb   = (unsigned short*)alloc((size_t)NSEG * T_TOK * INTERI * 2);
    int*            cnts = (int*)alloc(NEXP * 4);
    int*            lstp = (int*)alloc((size_t)NEXP * T_TOK * 4);
    float*          lstw = (float*)alloc((size_t)NEXP * T_TOK * 4);
    unsigned*       selp = (unsigned*)alloc((size_t)T_TOK * 4);
    float4*         selw = (float4*)alloc((size_t)T_TOK * 16);
    float*          Pb   = (float*)alloc((size_t)5 * T_TOK * DIMD * 4);

    cvt_all_kernel<<<28160, 256, 0, stream>>>(x, w1, w3, w2, ws1, ws3, ws2,
                                              xb, w1b, w3b, w2b, ws1b, ws3b, ws2b);
    gate_score_kernel<<<T_TOK / 4, 256, 0, stream>>>(x, gw, gb, selp, selw);
    build_lists_kernel<<<NEXP, 256, 0, stream>>>(selp, selw, cnts, lstp, lstw);
    gemm1_kernel<<<2176, 256, 0, stream>>>(xb, w1b, w3b, ws1b, ws3b, cnts, lstp, Hb);
    gemm2_kernel<<<4352, 256, 0, stream>>>(Hb, w2b, ws2b, cnts, lstp, lstw, Pb);
    combine_kernel<<<(T_TOK * DIMD / 4) / 256, 256, 0, stream>>>((const float4*)Pb, (float4*)d_out);
}

// Round 9
// 247.687 us; speedup vs baseline: 2.7302x; 1.0410x over previous
//
#include <hip/hip_runtime.h>

#define T_TOK  2048
#define DIMD   1024
#define INTERI 512
#define NEXP   16
#define NSEG   17   // 16 routed + 1 shared (index 16)

typedef __bf16 bf16x8 __attribute__((ext_vector_type(8)));
typedef float  f32x4  __attribute__((ext_vector_type(4)));

// XOR-swizzle: chunk c (8 elems) of row r lives at slot (c + (r>>1)) & 3.
// Makes b128 reads (lrow=lane&15 varying) conflict-free per quarter-wave.
#define SW(row, c) ((((c) + ((row) >> 1)) & 3) * 8)

// ---------- helpers ----------
__device__ __forceinline__ unsigned short f2b(float f) {
    union { float f; unsigned int u; } c; c.f = f;
    unsigned int u = c.u;
    unsigned int r = (u + 0x7FFFu + ((u >> 16) & 1u)) >> 16;  // RNE
    return (unsigned short)r;
}

// raw barrier: waits only LDS ops, leaves global loads in flight
__device__ __forceinline__ void lds_barrier() {
    asm volatile("s_waitcnt lgkmcnt(0)" ::: "memory");
    __builtin_amdgcn_s_barrier();
}

// ---------- fp32 -> bf16 conversion, all 7 tensors in one launch ----------
__global__ __launch_bounds__(256) void cvt_all_kernel(
    const float* __restrict__ x,  const float* __restrict__ w1,
    const float* __restrict__ w3, const float* __restrict__ w2,
    const float* __restrict__ ws1, const float* __restrict__ ws3,
    const float* __restrict__ ws2,
    unsigned short* __restrict__ xb,  unsigned short* __restrict__ w1b,
    unsigned short* __restrict__ w3b, unsigned short* __restrict__ w2b,
    unsigned short* __restrict__ ws1b, unsigned short* __restrict__ ws3b,
    unsigned short* __restrict__ ws2b)
{
    int g = blockIdx.x * 256 + threadIdx.x;
    const float* s; unsigned short* d; int i;
    if      (g < 524288)  { s = x;   d = xb;   i = g; }
    else if (g < 2621440) { s = w1;  d = w1b;  i = g - 524288; }
    else if (g < 4718592) { s = w3;  d = w3b;  i = g - 2621440; }
    else if (g < 6815744) { s = w2;  d = w2b;  i = g - 4718592; }
    else if (g < 6946816) { s = ws1; d = ws1b; i = g - 6815744; }
    else if (g < 7077888) { s = ws3; d = ws3b; i = g - 6946816; }
    else                  { s = ws2; d = ws2b; i = g - 7077888; }
    float4 v = ((const float4*)s)[i];
    ushort4 o;
    o.x = f2b(v.x); o.y = f2b(v.y); o.z = f2b(v.z); o.w = f2b(v.w);
    ((ushort4*)d)[i] = o;
}

// ---------- gate phase 1: scores + top-k selection, NO atomics ----------
__global__ __launch_bounds__(256) void gate_score_kernel(
    const float* __restrict__ x, const float* __restrict__ gw,
    const float* __restrict__ gb,
    unsigned* __restrict__ sel, float4* __restrict__ selw)
{
    int tok  = blockIdx.x * 4 + (threadIdx.x >> 6);   // one wave per token
    int lane = threadIdx.x & 63;
    const float* xp = x + (size_t)tok * DIMD;
    float xv[16];
#pragma unroll
    for (int j = 0; j < 16; ++j) xv[j] = xp[j * 64 + lane];

    float sc[16];
#pragma unroll
    for (int e = 0; e < 16; ++e) {
        const float* gwe = gw + e * DIMD;
        float p0 = 0.f, p1 = 0.f;
#pragma unroll
        for (int j = 0; j < 16; j += 2) {
            p0 += xv[j]     * gwe[j * 64 + lane];
            p1 += xv[j + 1] * gwe[(j + 1) * 64 + lane];
        }
        float p = p0 + p1;
#pragma unroll
        for (int o = 32; o; o >>= 1) p += __shfl_xor(p, o, 64);
        sc[e] = p;
    }
    if (lane != 0) return;

    float orig[16], s[16];
#pragma unroll
    for (int e = 0; e < 16; ++e) {
        orig[e] = 1.f / (1.f + expf(-sc[e]));
        s[e] = orig[e] + gb[e];
    }
    float gmax[4];
#pragma unroll
    for (int g = 0; g < 4; ++g) {
        float m = s[4 * g];
        for (int j = 1; j < 4; ++j) m = fmaxf(m, s[4 * g + j]);
        gmax[g] = m;
    }
    int g0 = 0;
    for (int g = 1; g < 4; ++g) if (gmax[g] > gmax[g0]) g0 = g;
    int g1 = -1;
    for (int g = 0; g < 4; ++g) { if (g == g0) continue; if (g1 < 0 || gmax[g] > gmax[g1]) g1 = g; }
    unsigned keep = (0xFu << (4 * g0)) | (0xFu << (4 * g1));
    unsigned used = 0;
    unsigned pk = 0;
    float w4[4];
    for (int j = 0; j < 4; ++j) {
        int best = -1;
        for (int e = 0; e < 16; ++e) {
            if (!((keep >> e) & 1u) || ((used >> e) & 1u)) continue;
            if (best < 0 || s[e] > s[best]) best = e;
        }
        used |= 1u << best;
        pk |= ((unsigned)best) << (4 * j);
        w4[j] = orig[best];
    }
    sel[tok] = pk;
    selw[tok] = make_float4(w4[0], w4[1], w4[2], w4[3]);
}

// ---------- gate phase 2: build per-expert token lists, NO atomics ----------
// lst entry packs token (low 16) | slot index (bits 16..17).
__global__ __launch_bounds__(256) void build_lists_kernel(
    const unsigned* __restrict__ sel, const float4* __restrict__ selw,
    int* __restrict__ counts, int* __restrict__ lst, float* __restrict__ lstw)
{
    const int e    = blockIdx.x;
    const int tid  = threadIdx.x;
    const int wave = tid >> 6;
    const int lane = tid & 63;

    __shared__ int wsum[4];
    __shared__ int basev;
    if (tid == 0) basev = 0;
    __syncthreads();

    for (int c = 0; c < T_TOK / 256; ++c) {
        int t = c * 256 + tid;
        unsigned s = sel[t];
        int match = -1;
#pragma unroll
        for (int j = 0; j < 4; ++j)
            if (((s >> (4 * j)) & 15u) == (unsigned)e) match = j;
        unsigned long long m = __ballot(match >= 0);
        int wpre = __popcll(m & ((1ull << lane) - 1ull));
        if (lane == 0) wsum[wave] = __popcll(m);
        __syncthreads();
        int pre = basev;
        for (int wv = 0; wv < wave; ++wv) pre += wsum[wv];
        if (match >= 0) {
            int pos = pre + wpre;
            lst [e * T_TOK + pos] = t | (match << 16);
            const float* wp = (const float*)&selw[t];
            lstw[e * T_TOK + pos] = wp[match];
        }
        __syncthreads();
        if (tid == 0) basev += wsum[0] + wsum[1] + wsum[2] + wsum[3];
        __syncthreads();
    }
    if (tid == 0) counts[e] = basev;
}

// ---------- GEMM1: H = silu(X W1^T) * (X W3^T) ----------
// Block tile 128m x 128n, wave tile 64x64 (dual h1/h3), BK=64 (2x32 panels).
// XCD-affine grid; swizzled LDS; register prefetch across lgkm-only barriers.
// grid: 1024 routed slots + 64 shared = 1088.
__global__ __launch_bounds__(256, 2) void gemm1_kernel(
    const unsigned short* __restrict__ xb,
    const unsigned short* __restrict__ w1b,
    const unsigned short* __restrict__ w3b,
    const unsigned short* __restrict__ ws1b,
    const unsigned short* __restrict__ ws3b,
    const int* __restrict__ counts,
    const int* __restrict__ lst,
    unsigned short* __restrict__ H)
{
    int b = blockIdx.x;
    int seg, mt, nt;
    if (b < 1024) {
        int xcd = b & 7, slot = b >> 3;     // slot 0..127
        seg = xcd + 8 * (slot >> 6);        // 2 experts per XCD
        int tile = slot & 63;
        mt = tile >> 2; nt = tile & 3;      // mt 0..15, nt 0..3
    } else {
        seg = NEXP;
        int tile = b - 1024;                // 0..63
        mt = tile >> 2; nt = tile & 3;
    }
    const int n_e = (seg == NEXP) ? T_TOK : counts[seg];
    const int m0  = mt * 128;
    if (m0 >= n_e) return;
    const int n0  = nt * 128;

    const unsigned short* w1p = (seg == NEXP) ? ws1b : w1b + (size_t)seg * INTERI * DIMD;
    const unsigned short* w3p = (seg == NEXP) ? ws3b : w3b + (size_t)seg * INTERI * DIMD;
    const int* lste = lst + seg * T_TOK;

    __shared__ __align__(16) unsigned short lA [2][128][32];   // 16 KB
    __shared__ __align__(16) unsigned short lB1[2][128][32];   // 16 KB
    __shared__ __align__(16) unsigned short lB3[2][128][32];   // 16 KB

    const int tid  = threadIdx.x;
    const int wave = tid >> 6;
    const int lane = tid & 63;
    const int quad = lane >> 4;
    const int lrow = lane & 15;
    const int r4   = tid >> 2;        // 0..63 staging row
    const int ct   = tid & 3;         // chunk index

    int ra0 = m0 + r4;       if (ra0 > n_e - 1) ra0 = n_e - 1;
    int ra1 = m0 + r4 + 64;  if (ra1 > n_e - 1) ra1 = n_e - 1;
    int tok0 = (seg == NEXP) ? ra0 : (lste[ra0] & 0xFFFF);
    int tok1 = (seg == NEXP) ? ra1 : (lste[ra1] & 0xFFFF);
    const unsigned short* gA0  = xb  + (size_t)tok0 * DIMD + ct * 8;
    const unsigned short* gA1  = xb  + (size_t)tok1 * DIMD + ct * 8;
    const unsigned short* gB1a = w1p + (size_t)(n0 + r4)      * DIMD + ct * 8;
    const unsigned short* gB1b = w1p + (size_t)(n0 + r4 + 64) * DIMD + ct * 8;
    const unsigned short* gB3a = w3p + (size_t)(n0 + r4)      * DIMD + ct * 8;
    const unsigned short* gB3b = w3p + (size_t)(n0 + r4 + 64) * DIMD + ct * 8;

    bf16x8 pa[2][2], pb1[2][2], pb3[2][2];   // [half][kk]

#define G1LOAD(k0) do { _Pragma("unroll") for (int kk = 0; kk < 2; ++kk) { \
    pa [0][kk] = *(const bf16x8*)(gA0  + (k0) + kk * 32); \
    pa [1][kk] = *(const bf16x8*)(gA1  + (k0) + kk * 32); \
    pb1[0][kk] = *(const bf16x8*)(gB1a + (k0) + kk * 32); \
    pb1[1][kk] = *(const bf16x8*)(gB1b + (k0) + kk * 32); \
    pb3[0][kk] = *(const bf16x8*)(gB3a + (k0) + kk * 32); \
    pb3[1][kk] = *(const bf16x8*)(gB3b + (k0) + kk * 32); } } while (0)

#define G1STORE() do { _Pragma("unroll") for (int kk = 0; kk < 2; ++kk) { \
    *(bf16x8*)&lA [kk][r4]     [SW(r4, ct)]      = pa [0][kk]; \
    *(bf16x8*)&lA [kk][64 + r4][SW(64 + r4, ct)] = pa [1][kk]; \
    *(bf16x8*)&lB1[kk][r4]     [SW(r4, ct)]      = pb1[0][kk]; \
    *(bf16x8*)&lB1[kk][64 + r4][SW(64 + r4, ct)] = pb1[1][kk]; \
    *(bf16x8*)&lB3[kk][r4]     [SW(r4, ct)]      = pb3[0][kk]; \
    *(bf16x8*)&lB3[kk][64 + r4][SW(64 + r4, ct)] = pb3[1][kk]; } } while (0)

    f32x4 acc1[4][4], acc3[4][4];
    const f32x4 zero = {0.f, 0.f, 0.f, 0.f};
#pragma unroll
    for (int i = 0; i < 4; ++i)
#pragma unroll
        for (int j = 0; j < 4; ++j) { acc1[i][j] = zero; acc3[i][j] = zero; }

    const int wm = (wave & 1) * 64;
    const int wn = (wave >> 1) * 64;

    G1LOAD(0);
    const int NK = DIMD / 64;  // 16
    for (int it = 0; it < NK; ++it) {
        G1STORE();
        lds_barrier();                       // writes visible; global loads stay in flight
        if (it + 1 < NK) G1LOAD((it + 1) * 64);
#pragma unroll
        for (int kk = 0; kk < 2; ++kk) {
            bf16x8 a[4], b1[4], b3[4];
#pragma unroll
            for (int t = 0; t < 4; ++t) {
                int rr = wm + t * 16 + lrow;
                a[t] = *(const bf16x8*)&lA[kk][rr][SW(rr, quad)];
            }
#pragma unroll
            for (int t = 0; t < 4; ++t) {
                int rc = wn + t * 16 + lrow;
                b1[t] = *(const bf16x8*)&lB1[kk][rc][SW(rc, quad)];
                b3[t] = *(const bf16x8*)&lB3[kk][rc][SW(rc, quad)];
            }
#pragma unroll
            for (int i = 0; i < 4; ++i)
#pragma unroll
                for (int j = 0; j < 4; ++j) {
                    acc1[i][j] = __builtin_amdgcn_mfma_f32_16x16x32_bf16(a[i], b1[j], acc1[i][j], 0, 0, 0);
                    acc3[i][j] = __builtin_amdgcn_mfma_f32_16x16x32_bf16(a[i], b3[j], acc3[i][j], 0, 0, 0);
                }
        }
        lds_barrier();                       // LDS reads done before next overwrite
    }
#undef G1LOAD
#undef G1STORE

    unsigned short* Hseg = H + (size_t)seg * T_TOK * INTERI;
#pragma unroll
    for (int i = 0; i < 4; ++i) {
        int rbase = m0 + wm + i * 16 + quad * 4;
#pragma unroll
        for (int r = 0; r < 4; ++r) {
            int row = rbase + r;
            if (row >= n_e) continue;
            unsigned short* hrow = Hseg + (size_t)row * INTERI + n0 + wn + lrow;
#pragma unroll
            for (int j = 0; j < 4; ++j) {
                float v1 = acc1[i][j][r];
                float v3 = acc3[i][j][r];
                float hv = (v1 / (1.f + __expf(-v1))) * v3;   // silu(v1)*v3
                hrow[j * 16] = f2b(hv);
            }
        }
    }
}

// ---------- GEMM2: P[slot] = w * (H W2^T), 128x128 tile, atomic-free ----------
// grid: 2048 routed slots + 128 shared = 2176.
__global__ __launch_bounds__(256, 2) void gemm2_kernel(
    const unsigned short* __restrict__ H,
    const unsigned short* __restrict__ w2b,
    const unsigned short* __restrict__ ws2b,
    const int* __restrict__ counts,
    const int* __restrict__ lst,
    const float* __restrict__ lstw,
    float* __restrict__ P)
{
    int b = blockIdx.x;
    int seg, mt, nt;
    if (b < 2048) {
        int xcd = b & 7, slot = b >> 3;     // 0..255
        seg = xcd + 8 * (slot >> 7);
        int tile = slot & 127;
        mt = tile >> 3; nt = tile & 7;      // mt 0..15, nt 0..7
    } else {
        seg = NEXP;
        int tile = b - 2048;                // 0..127
        mt = tile >> 3; nt = tile & 7;
    }
    const int n_e = (seg == NEXP) ? T_TOK : counts[seg];
    const int m0  = mt * 128;
    if (m0 >= n_e) return;
    const int n0  = nt * 128;

    const unsigned short* w2p  = (seg == NEXP) ? ws2b : w2b + (size_t)seg * DIMD * INTERI;
    const unsigned short* Hseg = H + (size_t)seg * T_TOK * INTERI;

    __shared__ __align__(16) unsigned short lA[2][128][32];   // 16 KB
    __shared__ __align__(16) unsigned short lB[2][128][32];   // 16 KB

    const int tid  = threadIdx.x;
    const int wave = tid >> 6;
    const int lane = tid & 63;
    const int quad = lane >> 4;
    const int lrow = lane & 15;
    const int r4   = tid >> 2;
    const int ct   = tid & 3;

    int ra0 = m0 + r4;       if (ra0 > n_e - 1) ra0 = n_e - 1;
    int ra1 = m0 + r4 + 64;  if (ra1 > n_e - 1) ra1 = n_e - 1;
    const unsigned short* gA0 = Hseg + (size_t)ra0 * INTERI + ct * 8;
    const unsigned short* gA1 = Hseg + (size_t)ra1 * INTERI + ct * 8;
    const unsigned short* gB0 = w2p + (size_t)(n0 + r4)      * INTERI + ct * 8;
    const unsigned short* gB1 = w2p + (size_t)(n0 + r4 + 64) * INTERI + ct * 8;

    bf16x8 pa[2][2], pb[2][2];

#define G2LOAD(k0) do { _Pragma("unroll") for (int kk = 0; kk < 2; ++kk) { \
    pa[0][kk] = *(const bf16x8*)(gA0 + (k0) + kk * 32); \
    pa[1][kk] = *(const bf16x8*)(gA1 + (k0) + kk * 32); \
    pb[0][kk] = *(const bf16x8*)(gB0 + (k0) + kk * 32); \
    pb[1][kk] = *(const bf16x8*)(gB1 + (k0) + kk * 32); } } while (0)

#define G2STORE() do { _Pragma("unroll") for (int kk = 0; kk < 2; ++kk) { \
    *(bf16x8*)&lA[kk][r4]     [SW(r4, ct)]      = pa[0][kk]; \
    *(bf16x8*)&lA[kk][64 + r4][SW(64 + r4, ct)] = pa[1][kk]; \
    *(bf16x8*)&lB[kk][r4]     [SW(r4, ct)]      = pb[0][kk]; \
    *(bf16x8*)&lB[kk][64 + r4][SW(64 + r4, ct)] = pb[1][kk]; } } while (0)

    f32x4 acc[4][4];
    const f32x4 zero = {0.f, 0.f, 0.f, 0.f};
#pragma unroll
    for (int i = 0; i < 4; ++i)
#pragma unroll
        for (int j = 0; j < 4; ++j) acc[i][j] = zero;

    const int wm = (wave & 1) * 64;
    const int wn = (wave >> 1) * 64;

    G2LOAD(0);
    const int NK = INTERI / 64;  // 8
    for (int it = 0; it < NK; ++it) {
        G2STORE();
        lds_barrier();
        if (it + 1 < NK) G2LOAD((it + 1) * 64);
#pragma unroll
        for (int kk = 0; kk < 2; ++kk) {
            bf16x8 a[4], bv[4];
#pragma unroll
            for (int t = 0; t < 4; ++t) {
                int rr = wm + t * 16 + lrow;
                a[t] = *(const bf16x8*)&lA[kk][rr][SW(rr, quad)];
            }
#pragma unroll
            for (int t = 0; t < 4; ++t) {
                int rc = wn + t * 16 + lrow;
                bv[t] = *(const bf16x8*)&lB[kk][rc][SW(rc, quad)];
            }
#pragma unroll
            for (int i = 0; i < 4; ++i)
#pragma unroll
                for (int j = 0; j < 4; ++j)
                    acc[i][j] = __builtin_amdgcn_mfma_f32_16x16x32_bf16(a[i], bv[j], acc[i][j], 0, 0, 0);
        }
        lds_barrier();
    }
#undef G2LOAD
#undef G2STORE

#pragma unroll
    for (int i = 0; i < 4; ++i) {
        int rbase = m0 + wm + i * 16 + quad * 4;
#pragma unroll
        for (int r = 0; r < 4; ++r) {
            int row = rbase + r;
            if (row >= n_e) continue;
            int tok, slot; float wt;
            if (seg == NEXP) { tok = row; slot = 4; wt = 1.f; }
            else {
                int ent = lst[seg * T_TOK + row];
                tok = ent & 0xFFFF; slot = ent >> 16;
                wt = lstw[seg * T_TOK + row];
            }
            float* prow = P + ((size_t)slot * T_TOK + tok) * DIMD + n0 + wn + lrow;
#pragma unroll
            for (int j = 0; j < 4; ++j)
                prow[j * 16] = wt * acc[i][j][r];
        }
    }
}

// ---------- combine: y = P0+P1+P2+P3+P4 ----------
__global__ __launch_bounds__(256) void combine_kernel(
    const float4* __restrict__ P, float4* __restrict__ y)
{
    const int i = blockIdx.x * 256 + threadIdx.x;   // over T*D/4
    const size_t plane = (size_t)T_TOK * DIMD / 4;
    float4 a = P[i];
    float4 b = P[plane + i];
    float4 c = P[2 * plane + i];
    float4 d = P[3 * plane + i];
    float4 e = P[4 * plane + i];
    float4 o;
    o.x = a.x + b.x + c.x + d.x + e.x;
    o.y = a.y + b.y + c.y + d.y + e.y;
    o.z = a.z + b.z + c.z + d.z + e.z;
    o.w = a.w + b.w + c.w + d.w + e.w;
    y[i] = o;
}

// ---------- launcher ----------
extern "C" void kernel_launch(void* const* d_in, const int* in_sizes, int n_in,
                              void* d_out, int out_size, void* d_ws, size_t ws_size,
                              hipStream_t stream)
{
    const float* x   = (const float*)d_in[0];
    const float* gw  = (const float*)d_in[1];
    const float* gb  = (const float*)d_in[2];
    const float* w1  = (const float*)d_in[3];
    const float* w2  = (const float*)d_in[4];
    const float* w3  = (const float*)d_in[5];
    const float* ws1 = (const float*)d_in[6];
    const float* ws2 = (const float*)d_in[7];
    const float* ws3 = (const float*)d_in[8];

    char* base = (char*)d_ws;
    size_t off = 0;
    auto alloc = [&](size_t bytes) {
        char* q = base + off; off += (bytes + 255) & ~(size_t)255; return q;
    };
    unsigned short* xb   = (unsigned short*)alloc((size_t)T_TOK * DIMD * 2);
    unsigned short* w1b  = (unsigned short*)alloc((size_t)NEXP * INTERI * DIMD * 2);
    unsigned short* w3b  = (unsigned short*)alloc((size_t)NEXP * INTERI * DIMD * 2);
    unsigned short* w2b  = (unsigned short*)alloc((size_t)NEXP * DIMD * INTERI * 2);
    unsigned short* ws1b = (unsigned short*)alloc((size_t)INTERI * DIMD * 2);
    unsigned short* ws3b = (unsigned short*)alloc((size_t)INTERI * DIMD * 2);
    unsigned short* ws2b = (unsigned short*)alloc((size_t)DIMD * INTERI * 2);
    unsigned short* Hb   = (unsigned short*)alloc((size_t)NSEG * T_TOK * INTERI * 2);
    int*            cnts = (int*)alloc(NEXP * 4);
    int*            lstp = (int*)alloc((size_t)NEXP * T_TOK * 4);
    float*          lstw = (float*)alloc((size_t)NEXP * T_TOK * 4);
    unsigned*       selp = (unsigned*)alloc((size_t)T_TOK * 4);
    float4*         selw = (float4*)alloc((size_t)T_TOK * 16);
    float*          Pb   = (float*)alloc((size_t)5 * T_TOK * DIMD * 4);

    cvt_all_kernel<<<28160, 256, 0, stream>>>(x, w1, w3, w2, ws1, ws3, ws2,
                                              xb, w1b, w3b, w2b, ws1b, ws3b, ws2b);
    gate_score_kernel<<<T_TOK / 4, 256, 0, stream>>>(x, gw, gb, selp, selw);
    build_lists_kernel<<<NEXP, 256, 0, stream>>>(selp, selw, cnts, lstp, lstw);
    gemm1_kernel<<<1088, 256, 0, stream>>>(xb, w1b, w3b, ws1b, ws3b, cnts, lstp, Hb);
    gemm2_kernel<<<2176, 256, 0, stream>>>(Hb, w2b, ws2b, cnts, lstp, lstw, Pb);
    combine_kernel<<<(T_TOK * DIMD / 4) / 256, 256, 0, stream>>>((const float4*)Pb, (float4*)d_out);
}